// Round 1
// baseline (2525.483 us; speedup 1.0000x reference)
//
#include <hip/hip_runtime.h>
#include <cmath>

#define NNODES 50000
#define NEDGES 600000
#define NBATCH 50

// ============================ CSR build ============================
__global__ void hist_kernel(const int* __restrict__ dst, int* __restrict__ deg){
  int e = blockIdx.x*blockDim.x + threadIdx.x;
  if(e < NEDGES) atomicAdd(&deg[dst[e]], 1);
}

__global__ void scan_kernel(const int* __restrict__ deg, int* __restrict__ off, int* __restrict__ cur){
  const int n = NNODES;
  const int CH = (n + 1023) / 1024;   // 49
  __shared__ int ps[1024];
  int t = threadIdx.x, base = t*CH;
  int s = 0;
  for(int i=0;i<CH;i++){ int id=base+i; if(id<n) s += deg[id]; }
  ps[t] = s; __syncthreads();
  for(int o=1;o<1024;o<<=1){
    int v = 0; if(t>=o) v = ps[t-o];
    __syncthreads();
    ps[t] += v;
    __syncthreads();
  }
  int run = ps[t] - s;   // exclusive prefix
  for(int i=0;i<CH;i++){
    int id = base+i; if(id > n) break;
    off[id] = run;
    if(id < n){ cur[id] = run; run += deg[id]; }
  }
}

__global__ void scatter_kernel(const int* __restrict__ src, const int* __restrict__ dst,
                               const float* __restrict__ ea, int* __restrict__ cur,
                               int* __restrict__ csr_src, float2* __restrict__ csr_ea){
  int e = blockIdx.x*blockDim.x + threadIdx.x;
  if(e >= NEDGES) return;
  int d = dst[e];
  int p = atomicAdd(&cur[d], 1);
  csr_src[p] = src[e];
  csr_ea[p] = make_float2(ea[2*e], ea[2*e+1]);
}

// ============================ conv0 linear (K=4) ============================
__global__ void gemm_k4(const float* __restrict__ x, const float* __restrict__ W,
                        const float* __restrict__ b, float* __restrict__ out){
  int idx = blockIdx.x*blockDim.x + threadIdx.x;
  if(idx >= NNODES*128) return;
  int r = idx >> 7, c = idx & 127;
  float acc = b[c];
  #pragma unroll
  for(int k=0;k<4;k++) acc += x[r*4+k] * W[k*128+c];
  out[idx] = acc;
}

// ============================ dual GEMM: xl = x@Wa+ba, xr = x@Wb+bb ============================
// x: [M,128], W: [128,128]. Tile 64 rows x 128 cols, per-thread 8x4 per matrix.
__launch_bounds__(256)
__global__ void gemm_dual(const float* __restrict__ x,
                          const float* __restrict__ Wa, const float* __restrict__ ba,
                          const float* __restrict__ Wb, const float* __restrict__ bb,
                          float* __restrict__ outa, float* __restrict__ outb, int M){
  __shared__ float xs[64][33];
  __shared__ float wsa[32][128];
  __shared__ float wsb[32][128];
  int tid = threadIdx.x;
  int tc = tid & 31, tr = tid >> 5;
  int row0 = blockIdx.x * 64;
  float acca[8][4], accb[8][4];
  #pragma unroll
  for(int i=0;i<8;i++){
    #pragma unroll
    for(int j=0;j<4;j++){ acca[i][j]=0.f; accb[i][j]=0.f; }
  }
  for(int kb=0;kb<128;kb+=32){
    #pragma unroll
    for(int i=0;i<8;i++){
      int l = tid + i*256;          // 0..2047
      int r = l >> 5, k = l & 31;
      int row = row0 + r;
      xs[r][k] = (row < M) ? x[row*128 + kb + k] : 0.f;
    }
    #pragma unroll
    for(int i=0;i<16;i++){
      int l = tid + i*256;          // 0..4095
      int k = l >> 7, c = l & 127;
      wsa[k][c] = Wa[(kb+k)*128 + c];
      wsb[k][c] = Wb[(kb+k)*128 + c];
    }
    __syncthreads();
    #pragma unroll 8
    for(int k=0;k<32;k++){
      float xv[8];
      #pragma unroll
      for(int i=0;i<8;i++) xv[i] = xs[tr*8+i][k];
      float4 wa = *(float4*)&wsa[k][tc*4];
      float4 wb = *(float4*)&wsb[k][tc*4];
      #pragma unroll
      for(int i=0;i<8;i++){
        acca[i][0] += xv[i]*wa.x; acca[i][1] += xv[i]*wa.y;
        acca[i][2] += xv[i]*wa.z; acca[i][3] += xv[i]*wa.w;
        accb[i][0] += xv[i]*wb.x; accb[i][1] += xv[i]*wb.y;
        accb[i][2] += xv[i]*wb.z; accb[i][3] += xv[i]*wb.w;
      }
    }
    __syncthreads();
  }
  float4 bva = *(const float4*)&ba[tc*4];
  float4 bvb = *(const float4*)&bb[tc*4];
  #pragma unroll
  for(int i=0;i<8;i++){
    int row = row0 + tr*8 + i;
    if(row < M){
      float4 oa = make_float4(acca[i][0]+bva.x, acca[i][1]+bva.y, acca[i][2]+bva.z, acca[i][3]+bva.w);
      float4 ob = make_float4(accb[i][0]+bvb.x, accb[i][1]+bvb.y, accb[i][2]+bvb.z, accb[i][3]+bvb.w);
      *(float4*)&outa[row*128 + tc*4] = oa;
      *(float4*)&outb[row*128 + tc*4] = ob;
    }
  }
}

// ============================ fused GATv2 edge phase ============================
// One wave (64 lanes) per destination node. Lane l owns channels 2l, 2l+1.
// Head of channel c is c/32 -> lanes [16h,16h+16) form head group h.
// Online softmax over incoming edges (self-loop handled explicitly, ea=0).
__launch_bounds__(256)
__global__ void edge_kernel(const float* __restrict__ xl, const float* __restrict__ xr,
                            const int* __restrict__ off, const int* __restrict__ csr_src,
                            const float2* __restrict__ csr_ea,
                            const float* __restrict__ We, const float* __restrict__ att,
                            const float* __restrict__ bias, const float* __restrict__ res,
                            float* __restrict__ out){
  int wid  = (blockIdx.x*blockDim.x + threadIdx.x) >> 6;
  int lane = threadIdx.x & 63;
  if(wid >= NNODES) return;
  int node = wid;
  int c0 = lane*2;
  float2 xr2 = *(const float2*)&xr[node*128 + c0];
  float2 xls = *(const float2*)&xl[node*128 + c0];
  float2 av  = *(const float2*)&att[c0];
  float2 w0  = *(const float2*)&We[c0];        // We[0][c]
  float2 w1  = *(const float2*)&We[128 + c0];  // We[1][c]

  // self-loop: src=node, ea=0
  float zx = xls.x + xr2.x; zx = zx > 0.f ? zx : 0.2f*zx;
  float zy = xls.y + xr2.y; zy = zy > 0.f ? zy : 0.2f*zy;
  float part = zx*av.x + zy*av.y;
  #pragma unroll
  for(int o=1;o<16;o<<=1) part += __shfl_xor(part, o, 64);
  float m = part;
  float den = 1.f;
  float accx = xls.x, accy = xls.y;

  int e0 = off[node], e1 = off[node+1];
  for(int e=e0;e<e1;e++){
    int s = csr_src[e];
    float2 ea = csr_ea[e];
    float2 xv = *(const float2*)&xl[s*128 + c0];
    float z0 = xv.x + xr2.x + ea.x*w0.x + ea.y*w1.x; z0 = z0 > 0.f ? z0 : 0.2f*z0;
    float z1 = xv.y + xr2.y + ea.x*w0.y + ea.y*w1.y; z1 = z1 > 0.f ? z1 : 0.2f*z1;
    float p = z0*av.x + z1*av.y;
    #pragma unroll
    for(int o=1;o<16;o<<=1) p += __shfl_xor(p, o, 64);
    float nm = fmaxf(m, p);
    float sc = __expf(m - nm);
    float pe = __expf(p - nm);
    den  = den*sc + pe;
    accx = accx*sc + pe*xv.x;
    accy = accy*sc + pe*xv.y;
    m = nm;
  }
  float inv = 1.f/(den + 1e-16f);
  float ox = accx*inv + bias[c0];
  float oy = accy*inv + bias[c0+1];
  ox = ox > 0.f ? ox : 0.f;   // relu on every conv output
  oy = oy > 0.f ? oy : 0.f;
  if(res){ ox += res[node*128 + c0]; oy += res[node*128 + c0 + 1]; }
  *(float2*)&out[node*128 + c0] = make_float2(ox, oy);
}

// ============================ pooling ============================
__global__ void pool_kernel(const float* __restrict__ x, const int* __restrict__ batch,
                            float* __restrict__ sums, float* __restrict__ maxv,
                            float* __restrict__ cnt){
  int idx = blockIdx.x*blockDim.x + threadIdx.x;
  if(idx >= NNODES*64) return;
  int node = idx >> 6, c2 = idx & 63;
  int b = batch[node];
  float2 v = *(const float2*)&x[node*128 + c2*2];
  atomicAdd(&sums[b*128 + c2*2],     v.x);
  atomicAdd(&sums[b*128 + c2*2 + 1], v.y);
  // x >= 0 always (relu chain + nonneg residuals) -> int-bits ordering valid, init 0
  atomicMax((int*)&maxv[b*128 + c2*2],     __float_as_int(v.x));
  atomicMax((int*)&maxv[b*128 + c2*2 + 1], __float_as_int(v.y));
  if(c2 == 0) atomicAdd(&cnt[b], 1.f);
}

__global__ void pool_fin(const float* __restrict__ sums, const float* __restrict__ maxv,
                         const float* __restrict__ cnt, float* __restrict__ X){
  int idx = blockIdx.x*blockDim.x + threadIdx.x;
  if(idx >= NBATCH*128) return;
  int b = idx >> 7, c = idx & 127;
  float ct = cnt[b]; ct = ct > 1.f ? ct : 1.f;
  X[b*256 + c]       = sums[idx] / ct;
  X[b*256 + 128 + c] = maxv[idx];
}

// ============================ dense layers ============================
// act: 0=none, 1=relu, 2=tanh
__global__ void dense_kernel(const float* __restrict__ in, const float* __restrict__ W,
                             const float* __restrict__ b, float* __restrict__ out,
                             int M, int K, int N, int act, int ostride){
  int idx = blockIdx.x*blockDim.x + threadIdx.x;
  if(idx >= M*N) return;
  int r = idx / N, c = idx - r*N;
  float acc = b[c];
  for(int k=0;k<K;k++) acc += in[r*K+k] * W[k*N+c];
  if(act == 1) acc = fmaxf(acc, 0.f);
  else if(act == 2) acc = tanhf(acc);
  out[r*ostride + c] = acc;
}

// ============================ launch ============================
extern "C" void kernel_launch(void* const* d_in, const int* in_sizes, int n_in,
                              void* d_out, int out_size, void* d_ws, size_t ws_size,
                              hipStream_t stream) {
  const float* nodes  = (const float*)d_in[0];
  const int*   eidx   = (const int*)  d_in[1];   // [2, 600000]
  const float* eattr  = (const float*)d_in[2];   // [600000, 2]
  const int*   batch  = (const int*)  d_in[3];
  const float* W0l    = (const float*)d_in[4];
  const float* b0l    = (const float*)d_in[5];
  const float* W0r    = (const float*)d_in[6];
  const float* b0r    = (const float*)d_in[7];
  const float* W0e    = (const float*)d_in[8];
  const float* att0   = (const float*)d_in[9];
  const float* bias0  = (const float*)d_in[10];
  const float* Wl     = (const float*)d_in[11];  // [8,128,128]
  const float* bl     = (const float*)d_in[12];
  const float* Wr     = (const float*)d_in[13];
  const float* br     = (const float*)d_in[14];
  const float* We     = (const float*)d_in[15];  // [8,2,128]
  const float* atts   = (const float*)d_in[16];  // [8,4,32]
  const float* biases = (const float*)d_in[17];
  const float* D1_W   = (const float*)d_in[18];
  const float* D1_b   = (const float*)d_in[19];
  const float* D23_W  = (const float*)d_in[20];
  const float* D23_b  = (const float*)d_in[21];
  const float* H1_W   = (const float*)d_in[22];
  const float* H1_b   = (const float*)d_in[23];
  const float* H2_W   = (const float*)d_in[24];
  const float* H2_b   = (const float*)d_in[25];
  const float* H3_W   = (const float*)d_in[26];
  const float* H3_b   = (const float*)d_in[27];

  // ---- workspace layout ----
  char* ws = (char*)d_ws;
  size_t o = 0;
  auto alloc = [&](size_t bytes)->char*{ char* p = ws + o; o = (o + bytes + 255) & ~(size_t)255; return p; };
  int*    deg     = (int*)   alloc(NNODES*4);
  int*    offs    = (int*)   alloc((NNODES+1)*4);
  int*    cur     = (int*)   alloc(NNODES*4);
  int*    csr_src = (int*)   alloc(NEDGES*4);
  float2* csr_ea  = (float2*)alloc(NEDGES*8);
  float*  xl      = (float*) alloc((size_t)NNODES*128*4);
  float*  xr      = (float*) alloc((size_t)NNODES*128*4);
  float*  bufA    = (float*) alloc((size_t)NNODES*128*4);
  float*  bufB    = (float*) alloc((size_t)NNODES*128*4);
  float*  pool    = (float*) alloc((NBATCH*128*2 + NBATCH)*4); // sums, maxv, cnt contiguous
  float*  sums    = pool;
  float*  maxv    = pool + NBATCH*128;
  float*  cnt     = pool + NBATCH*256;
  float*  X       = (float*) alloc(NBATCH*256*4);
  float*  t1      = (float*) alloc(NBATCH*128*4);
  float*  t2      = (float*) alloc(NBATCH*128*4);
  float*  t3      = (float*) alloc(NBATCH*64*4);
  (void)ws_size; (void)in_sizes; (void)n_in; (void)out_size;

  const int* src = eidx;
  const int* dst = eidx + NEDGES;

  // ---- CSR build (real edges only; self-loops handled in edge_kernel) ----
  hipMemsetAsync(deg, 0, NNODES*4, stream);
  hipMemsetAsync(pool, 0, (NBATCH*128*2 + NBATCH)*4, stream);
  hist_kernel<<<(NEDGES+255)/256, 256, 0, stream>>>(dst, deg);
  scan_kernel<<<1, 1024, 0, stream>>>(deg, offs, cur);
  scatter_kernel<<<(NEDGES+255)/256, 256, 0, stream>>>(src, dst, eattr, cur, csr_src, csr_ea);

  // ---- conv0 ----
  gemm_k4<<<(NNODES*128+255)/256, 256, 0, stream>>>(nodes, W0l, b0l, xl);
  gemm_k4<<<(NNODES*128+255)/256, 256, 0, stream>>>(nodes, W0r, b0r, xr);
  edge_kernel<<<(NNODES+3)/4, 256, 0, stream>>>(xl, xr, offs, csr_src, csr_ea,
                                                W0e, att0, bias0, nullptr, bufA);

  // ---- 4 skip blocks x 2 convs ----
  const int gemm_grid = (NNODES + 63) / 64;
  for(int blk=0; blk<4; blk++){
    int j = 2*blk;
    gemm_dual<<<gemm_grid, 256, 0, stream>>>(bufA, Wl + (size_t)j*16384, bl + j*128,
                                             Wr + (size_t)j*16384, br + j*128, xl, xr, NNODES);
    edge_kernel<<<(NNODES+3)/4, 256, 0, stream>>>(xl, xr, offs, csr_src, csr_ea,
                                                  We + j*256, atts + j*128, biases + j*128,
                                                  nullptr, bufB);
    j = 2*blk + 1;
    gemm_dual<<<gemm_grid, 256, 0, stream>>>(bufB, Wl + (size_t)j*16384, bl + j*128,
                                             Wr + (size_t)j*16384, br + j*128, xl, xr, NNODES);
    edge_kernel<<<(NNODES+3)/4, 256, 0, stream>>>(xl, xr, offs, csr_src, csr_ea,
                                                  We + j*256, atts + j*128, biases + j*128,
                                                  bufA /*residual*/, bufA);
  }

  // ---- pooling ----
  pool_kernel<<<(NNODES*64+255)/256, 256, 0, stream>>>(bufA, batch, sums, maxv, cnt);
  pool_fin<<<(NBATCH*128+255)/256, 256, 0, stream>>>(sums, maxv, cnt, X);

  // ---- dense trunk ----
  dense_kernel<<<(NBATCH*128+255)/256, 256, 0, stream>>>(X,  D1_W,          D1_b,        t1, NBATCH, 256, 128, 1, 128);
  dense_kernel<<<(NBATCH*128+255)/256, 256, 0, stream>>>(t1, D23_W,         D23_b,       t2, NBATCH, 128, 128, 1, 128);
  dense_kernel<<<(NBATCH*128+255)/256, 256, 0, stream>>>(t2, D23_W + 16384, D23_b + 128, t1, NBATCH, 128, 128, 1, 128);

  // ---- 3 heads ----
  for(int h=0; h<3; h++){
    dense_kernel<<<(NBATCH*128+255)/256, 256, 0, stream>>>(t1, H1_W + (size_t)h*16384, H1_b + h*128, t2, NBATCH, 128, 128, 1, 128);
    dense_kernel<<<(NBATCH*64+255)/256, 256, 0, stream>>>(t2, H2_W + (size_t)h*8192,  H2_b + h*64,  t3, NBATCH, 128, 64, 1, 64);
    dense_kernel<<<1, 64, 0, stream>>>(t3, H3_W + (size_t)h*64, H3_b + h, (float*)d_out + h, NBATCH, 64, 1, (h==0)?2:0, 3);
  }
}

// Round 2
// 2091.955 us; speedup vs baseline: 1.2072x; 1.2072x over previous
//
#include <hip/hip_runtime.h>
#include <cmath>

#define NNODES 50000
#define NEDGES 600000
#define NBATCH 50

// ============================ CSR build ============================
__global__ void hist_kernel(const int* __restrict__ dst, int* __restrict__ deg){
  int e = blockIdx.x*blockDim.x + threadIdx.x;
  if(e < NEDGES) atomicAdd(&deg[dst[e]], 1);
}

__global__ void scan_kernel(const int* __restrict__ deg, int* __restrict__ off, int* __restrict__ cur){
  const int n = NNODES;
  const int CH = (n + 1023) / 1024;   // 49
  __shared__ int ps[1024];
  int t = threadIdx.x, base = t*CH;
  int s = 0;
  for(int i=0;i<CH;i++){ int id=base+i; if(id<n) s += deg[id]; }
  ps[t] = s; __syncthreads();
  for(int o=1;o<1024;o<<=1){
    int v = 0; if(t>=o) v = ps[t-o];
    __syncthreads();
    ps[t] += v;
    __syncthreads();
  }
  int run = ps[t] - s;   // exclusive prefix
  for(int i=0;i<CH;i++){
    int id = base+i; if(id > n) break;
    off[id] = run;
    if(id < n){ cur[id] = run; run += deg[id]; }
  }
}

__global__ void scatter_kernel(const int* __restrict__ src, const int* __restrict__ dst,
                               const float* __restrict__ ea, int* __restrict__ cur,
                               int* __restrict__ csr_src, float2* __restrict__ csr_ea){
  int e = blockIdx.x*blockDim.x + threadIdx.x;
  if(e >= NEDGES) return;
  int d = dst[e];
  int p = atomicAdd(&cur[d], 1);
  csr_src[p] = src[e];
  csr_ea[p] = make_float2(ea[2*e], ea[2*e+1]);
}

// ============================ conv0 linear (K=4) ============================
__global__ void gemm_k4(const float* __restrict__ x, const float* __restrict__ W,
                        const float* __restrict__ b, float* __restrict__ out){
  int idx = blockIdx.x*blockDim.x + threadIdx.x;
  if(idx >= NNODES*128) return;
  int r = idx >> 7, c = idx & 127;
  float acc = b[c];
  #pragma unroll
  for(int k=0;k<4;k++) acc += x[r*4+k] * W[k*128+c];
  out[idx] = acc;
}

// ============================ dual GEMM: xl = x@Wa+ba, xr = x@Wb+bb ============================
// x: [M,128], W: [128,128]. Tile 64 rows x 128 cols, per-thread 8x4 per matrix.
__launch_bounds__(256)
__global__ void gemm_dual(const float* __restrict__ x,
                          const float* __restrict__ Wa, const float* __restrict__ ba,
                          const float* __restrict__ Wb, const float* __restrict__ bb,
                          float* __restrict__ outa, float* __restrict__ outb, int M){
  __shared__ float xs[64][33];
  __shared__ float wsa[32][128];
  __shared__ float wsb[32][128];
  int tid = threadIdx.x;
  int tc = tid & 31, tr = tid >> 5;
  int row0 = blockIdx.x * 64;
  float acca[8][4], accb[8][4];
  #pragma unroll
  for(int i=0;i<8;i++){
    #pragma unroll
    for(int j=0;j<4;j++){ acca[i][j]=0.f; accb[i][j]=0.f; }
  }
  for(int kb=0;kb<128;kb+=32){
    #pragma unroll
    for(int i=0;i<8;i++){
      int l = tid + i*256;          // 0..2047
      int r = l >> 5, k = l & 31;
      int row = row0 + r;
      xs[r][k] = (row < M) ? x[row*128 + kb + k] : 0.f;
    }
    #pragma unroll
    for(int i=0;i<16;i++){
      int l = tid + i*256;          // 0..4095
      int k = l >> 7, c = l & 127;
      wsa[k][c] = Wa[(kb+k)*128 + c];
      wsb[k][c] = Wb[(kb+k)*128 + c];
    }
    __syncthreads();
    #pragma unroll 8
    for(int k=0;k<32;k++){
      float xv[8];
      #pragma unroll
      for(int i=0;i<8;i++) xv[i] = xs[tr*8+i][k];
      float4 wa = *(float4*)&wsa[k][tc*4];
      float4 wb = *(float4*)&wsb[k][tc*4];
      #pragma unroll
      for(int i=0;i<8;i++){
        acca[i][0] += xv[i]*wa.x; acca[i][1] += xv[i]*wa.y;
        acca[i][2] += xv[i]*wa.z; acca[i][3] += xv[i]*wa.w;
        accb[i][0] += xv[i]*wb.x; accb[i][1] += xv[i]*wb.y;
        accb[i][2] += xv[i]*wb.z; accb[i][3] += xv[i]*wb.w;
      }
    }
    __syncthreads();
  }
  float4 bva = *(const float4*)&ba[tc*4];
  float4 bvb = *(const float4*)&bb[tc*4];
  #pragma unroll
  for(int i=0;i<8;i++){
    int row = row0 + tr*8 + i;
    if(row < M){
      float4 oa = make_float4(acca[i][0]+bva.x, acca[i][1]+bva.y, acca[i][2]+bva.z, acca[i][3]+bva.w);
      float4 ob = make_float4(accb[i][0]+bvb.x, accb[i][1]+bvb.y, accb[i][2]+bvb.z, accb[i][3]+bvb.w);
      *(float4*)&outa[row*128 + tc*4] = oa;
      *(float4*)&outb[row*128 + tc*4] = ob;
    }
  }
}

// ============================ fused GATv2 edge phase ============================
// One wave (64 lanes) per destination node. Lane l owns channels 2l, 2l+1.
// Head of channel c is c/32 -> lanes [16h,16h+16) form head group h.
// Online softmax over incoming edges (self-loop handled explicitly, ea=0).
__launch_bounds__(256)
__global__ void edge_kernel(const float* __restrict__ xl, const float* __restrict__ xr,
                            const int* __restrict__ off, const int* __restrict__ csr_src,
                            const float2* __restrict__ csr_ea,
                            const float* __restrict__ We, const float* __restrict__ att,
                            const float* __restrict__ bias, const float* __restrict__ res,
                            float* __restrict__ out){
  int wid  = (blockIdx.x*blockDim.x + threadIdx.x) >> 6;
  int lane = threadIdx.x & 63;
  if(wid >= NNODES) return;
  int node = wid;
  int c0 = lane*2;
  float2 xr2 = *(const float2*)&xr[node*128 + c0];
  float2 xls = *(const float2*)&xl[node*128 + c0];
  float2 av  = *(const float2*)&att[c0];
  float2 w0  = *(const float2*)&We[c0];        // We[0][c]
  float2 w1  = *(const float2*)&We[128 + c0];  // We[1][c]

  // self-loop: src=node, ea=0
  float zx = xls.x + xr2.x; zx = zx > 0.f ? zx : 0.2f*zx;
  float zy = xls.y + xr2.y; zy = zy > 0.f ? zy : 0.2f*zy;
  float part = zx*av.x + zy*av.y;
  #pragma unroll
  for(int o=1;o<16;o<<=1) part += __shfl_xor(part, o, 64);
  float m = part;
  float den = 1.f;
  float accx = xls.x, accy = xls.y;

  int e0 = off[node], e1 = off[node+1];
  for(int e=e0;e<e1;e++){
    int s = csr_src[e];
    float2 ea = csr_ea[e];
    float2 xv = *(const float2*)&xl[s*128 + c0];
    float z0 = xv.x + xr2.x + ea.x*w0.x + ea.y*w1.x; z0 = z0 > 0.f ? z0 : 0.2f*z0;
    float z1 = xv.y + xr2.y + ea.x*w0.y + ea.y*w1.y; z1 = z1 > 0.f ? z1 : 0.2f*z1;
    float p = z0*av.x + z1*av.y;
    #pragma unroll
    for(int o=1;o<16;o<<=1) p += __shfl_xor(p, o, 64);
    float nm = fmaxf(m, p);
    float sc = __expf(m - nm);
    float pe = __expf(p - nm);
    den  = den*sc + pe;
    accx = accx*sc + pe*xv.x;
    accy = accy*sc + pe*xv.y;
    m = nm;
  }
  float inv = 1.f/(den + 1e-16f);
  float ox = accx*inv + bias[c0];
  float oy = accy*inv + bias[c0+1];
  ox = ox > 0.f ? ox : 0.f;   // relu on every conv output
  oy = oy > 0.f ? oy : 0.f;
  if(res){ ox += res[node*128 + c0]; oy += res[node*128 + c0 + 1]; }
  *(float2*)&out[node*128 + c0] = make_float2(ox, oy);
}

// ============================ pooling ============================
// batch[] is SORTED. One block of 128 threads (thread = channel) scans a
// contiguous chunk of nodes, accumulating sum/max in registers per batch
// segment; flushes one atomic per (segment, channel). Atomic count drops
// from 12.8M (old per-element version) to ~100k.
#define POOL_CHUNK 128
__launch_bounds__(128)
__global__ void pool_kernel(const float* __restrict__ x, const int* __restrict__ batch,
                            float* __restrict__ sums, float* __restrict__ maxv,
                            float* __restrict__ cnt){
  int c = threadIdx.x;                  // channel 0..127
  int n0 = blockIdx.x * POOL_CHUNK;
  if(n0 >= NNODES) return;
  int n1 = n0 + POOL_CHUNK; if(n1 > NNODES) n1 = NNODES;
  int curb = batch[n0];
  float s = 0.f, mx = 0.f;              // x >= 0 (relu chain) -> 0 is safe max-identity
  float segc = 0.f;
  for(int nd = n0; nd < n1; nd++){
    int b = batch[nd];                  // wave-uniform (sorted), L1-hit
    if(b != curb){                      // uniform branch, rare
      atomicAdd(&sums[curb*128 + c], s);
      atomicMax((int*)&maxv[curb*128 + c], __float_as_int(mx));
      if(c == 0) atomicAdd(&cnt[curb], segc);
      curb = b; s = 0.f; mx = 0.f; segc = 0.f;
    }
    float v = x[nd*128 + c];            // coalesced 512B/wave-pair
    s += v; mx = fmaxf(mx, v); segc += 1.f;
  }
  atomicAdd(&sums[curb*128 + c], s);
  atomicMax((int*)&maxv[curb*128 + c], __float_as_int(mx));
  if(c == 0) atomicAdd(&cnt[curb], segc);
}

__global__ void pool_fin(const float* __restrict__ sums, const float* __restrict__ maxv,
                         const float* __restrict__ cnt, float* __restrict__ X){
  int idx = blockIdx.x*blockDim.x + threadIdx.x;
  if(idx >= NBATCH*128) return;
  int b = idx >> 7, c = idx & 127;
  float ct = cnt[b]; ct = ct > 1.f ? ct : 1.f;
  X[b*256 + c]       = sums[idx] / ct;
  X[b*256 + 128 + c] = maxv[idx];
}

// ============================ dense layers ============================
// act: 0=none, 1=relu, 2=tanh
__global__ void dense_kernel(const float* __restrict__ in, const float* __restrict__ W,
                             const float* __restrict__ b, float* __restrict__ out,
                             int M, int K, int N, int act, int ostride){
  int idx = blockIdx.x*blockDim.x + threadIdx.x;
  if(idx >= M*N) return;
  int r = idx / N, c = idx - r*N;
  float acc = b[c];
  for(int k=0;k<K;k++) acc += in[r*K+k] * W[k*N+c];
  if(act == 1) acc = fmaxf(acc, 0.f);
  else if(act == 2) acc = tanhf(acc);
  out[r*ostride + c] = acc;
}

// ============================ launch ============================
extern "C" void kernel_launch(void* const* d_in, const int* in_sizes, int n_in,
                              void* d_out, int out_size, void* d_ws, size_t ws_size,
                              hipStream_t stream) {
  const float* nodes  = (const float*)d_in[0];
  const int*   eidx   = (const int*)  d_in[1];   // [2, 600000]
  const float* eattr  = (const float*)d_in[2];   // [600000, 2]
  const int*   batch  = (const int*)  d_in[3];
  const float* W0l    = (const float*)d_in[4];
  const float* b0l    = (const float*)d_in[5];
  const float* W0r    = (const float*)d_in[6];
  const float* b0r    = (const float*)d_in[7];
  const float* W0e    = (const float*)d_in[8];
  const float* att0   = (const float*)d_in[9];
  const float* bias0  = (const float*)d_in[10];
  const float* Wl     = (const float*)d_in[11];  // [8,128,128]
  const float* bl     = (const float*)d_in[12];
  const float* Wr     = (const float*)d_in[13];
  const float* br     = (const float*)d_in[14];
  const float* We     = (const float*)d_in[15];  // [8,2,128]
  const float* atts   = (const float*)d_in[16];  // [8,4,32]
  const float* biases = (const float*)d_in[17];
  const float* D1_W   = (const float*)d_in[18];
  const float* D1_b   = (const float*)d_in[19];
  const float* D23_W  = (const float*)d_in[20];
  const float* D23_b  = (const float*)d_in[21];
  const float* H1_W   = (const float*)d_in[22];
  const float* H1_b   = (const float*)d_in[23];
  const float* H2_W   = (const float*)d_in[24];
  const float* H2_b   = (const float*)d_in[25];
  const float* H3_W   = (const float*)d_in[26];
  const float* H3_b   = (const float*)d_in[27];

  // ---- workspace layout ----
  char* ws = (char*)d_ws;
  size_t o = 0;
  auto alloc = [&](size_t bytes)->char*{ char* p = ws + o; o = (o + bytes + 255) & ~(size_t)255; return p; };
  int*    deg     = (int*)   alloc(NNODES*4);
  int*    offs    = (int*)   alloc((NNODES+1)*4);
  int*    cur     = (int*)   alloc(NNODES*4);
  int*    csr_src = (int*)   alloc(NEDGES*4);
  float2* csr_ea  = (float2*)alloc(NEDGES*8);
  float*  xl      = (float*) alloc((size_t)NNODES*128*4);
  float*  xr      = (float*) alloc((size_t)NNODES*128*4);
  float*  bufA    = (float*) alloc((size_t)NNODES*128*4);
  float*  bufB    = (float*) alloc((size_t)NNODES*128*4);
  float*  pool    = (float*) alloc((NBATCH*128*2 + NBATCH)*4); // sums, maxv, cnt contiguous
  float*  sums    = pool;
  float*  maxv    = pool + NBATCH*128;
  float*  cnt     = pool + NBATCH*256;
  float*  X       = (float*) alloc(NBATCH*256*4);
  float*  t1      = (float*) alloc(NBATCH*128*4);
  float*  t2      = (float*) alloc(NBATCH*128*4);
  float*  t3      = (float*) alloc(NBATCH*64*4);
  (void)ws_size; (void)in_sizes; (void)n_in; (void)out_size;

  const int* src = eidx;
  const int* dst = eidx + NEDGES;

  // ---- CSR build (real edges only; self-loops handled in edge_kernel) ----
  hipMemsetAsync(deg, 0, NNODES*4, stream);
  hipMemsetAsync(pool, 0, (NBATCH*128*2 + NBATCH)*4, stream);
  hist_kernel<<<(NEDGES+255)/256, 256, 0, stream>>>(dst, deg);
  scan_kernel<<<1, 1024, 0, stream>>>(deg, offs, cur);
  scatter_kernel<<<(NEDGES+255)/256, 256, 0, stream>>>(src, dst, eattr, cur, csr_src, csr_ea);

  // ---- conv0 ----
  gemm_k4<<<(NNODES*128+255)/256, 256, 0, stream>>>(nodes, W0l, b0l, xl);
  gemm_k4<<<(NNODES*128+255)/256, 256, 0, stream>>>(nodes, W0r, b0r, xr);
  edge_kernel<<<(NNODES+3)/4, 256, 0, stream>>>(xl, xr, offs, csr_src, csr_ea,
                                                W0e, att0, bias0, nullptr, bufA);

  // ---- 4 skip blocks x 2 convs ----
  const int gemm_grid = (NNODES + 63) / 64;
  for(int blk=0; blk<4; blk++){
    int j = 2*blk;
    gemm_dual<<<gemm_grid, 256, 0, stream>>>(bufA, Wl + (size_t)j*16384, bl + j*128,
                                             Wr + (size_t)j*16384, br + j*128, xl, xr, NNODES);
    edge_kernel<<<(NNODES+3)/4, 256, 0, stream>>>(xl, xr, offs, csr_src, csr_ea,
                                                  We + j*256, atts + j*128, biases + j*128,
                                                  nullptr, bufB);
    j = 2*blk + 1;
    gemm_dual<<<gemm_grid, 256, 0, stream>>>(bufB, Wl + (size_t)j*16384, bl + j*128,
                                             Wr + (size_t)j*16384, br + j*128, xl, xr, NNODES);
    edge_kernel<<<(NNODES+3)/4, 256, 0, stream>>>(xl, xr, offs, csr_src, csr_ea,
                                                  We + j*256, atts + j*128, biases + j*128,
                                                  bufA /*residual*/, bufA);
  }

  // ---- pooling ----
  pool_kernel<<<(NNODES + POOL_CHUNK - 1)/POOL_CHUNK, 128, 0, stream>>>(bufA, batch, sums, maxv, cnt);
  pool_fin<<<(NBATCH*128+255)/256, 256, 0, stream>>>(sums, maxv, cnt, X);

  // ---- dense trunk ----
  dense_kernel<<<(NBATCH*128+255)/256, 256, 0, stream>>>(X,  D1_W,          D1_b,        t1, NBATCH, 256, 128, 1, 128);
  dense_kernel<<<(NBATCH*128+255)/256, 256, 0, stream>>>(t1, D23_W,         D23_b,       t2, NBATCH, 128, 128, 1, 128);
  dense_kernel<<<(NBATCH*128+255)/256, 256, 0, stream>>>(t2, D23_W + 16384, D23_b + 128, t1, NBATCH, 128, 128, 1, 128);

  // ---- 3 heads ----
  for(int h=0; h<3; h++){
    dense_kernel<<<(NBATCH*128+255)/256, 256, 0, stream>>>(t1, H1_W + (size_t)h*16384, H1_b + h*128, t2, NBATCH, 128, 128, 1, 128);
    dense_kernel<<<(NBATCH*64+255)/256, 256, 0, stream>>>(t2, H2_W + (size_t)h*8192,  H2_b + h*64,  t3, NBATCH, 128, 64, 1, 64);
    dense_kernel<<<1, 64, 0, stream>>>(t3, H3_W + (size_t)h*64, H3_b + h, (float*)d_out + h, NBATCH, 64, 1, (h==0)?2:0, 3);
  }
}

// Round 3
// 1986.066 us; speedup vs baseline: 1.2716x; 1.0533x over previous
//
#include <hip/hip_runtime.h>
#include <cmath>

#define NNODES 50000
#define NEDGES 600000
#define NBATCH 50
#define SCAN_BLOCK 256
#define NCHUNK ((NNODES + SCAN_BLOCK - 1) / SCAN_BLOCK)   // 196

// ============================ CSR build ============================
__global__ void hist_kernel(const int* __restrict__ dst, int* __restrict__ deg){
  int e = blockIdx.x*blockDim.x + threadIdx.x;
  if(e < NEDGES) atomicAdd(&deg[dst[e]], 1);
}

// two-level scan: (1) per-block sums, (2) scan of block sums, (3) per-block scan + base
__global__ void deg_partial(const int* __restrict__ deg, int* __restrict__ part){
  __shared__ int red[SCAN_BLOCK];
  int t = threadIdx.x, id = blockIdx.x*SCAN_BLOCK + t;
  red[t] = (id < NNODES) ? deg[id] : 0;
  __syncthreads();
  for(int o = SCAN_BLOCK/2; o > 0; o >>= 1){
    if(t < o) red[t] += red[t+o];
    __syncthreads();
  }
  if(t == 0) part[blockIdx.x] = red[0];
}

__global__ void part_scan(int* __restrict__ part){
  __shared__ int ps[256];
  int t = threadIdx.x;
  int v = (t < NCHUNK) ? part[t] : 0;
  ps[t] = v; __syncthreads();
  for(int o=1;o<256;o<<=1){
    int u = (t>=o) ? ps[t-o] : 0;
    __syncthreads();
    ps[t] += u;
    __syncthreads();
  }
  if(t < NCHUNK) part[t] = ps[t] - v;   // exclusive
}

__global__ void scan_final(const int* __restrict__ deg, const int* __restrict__ part,
                           int* __restrict__ off, int* __restrict__ cur){
  __shared__ int ps[SCAN_BLOCK];
  int t = threadIdx.x, id = blockIdx.x*SCAN_BLOCK + t;
  int v = (id < NNODES) ? deg[id] : 0;
  ps[t] = v; __syncthreads();
  for(int o=1;o<SCAN_BLOCK;o<<=1){
    int u = (t>=o) ? ps[t-o] : 0;
    __syncthreads();
    ps[t] += u;
    __syncthreads();
  }
  int excl = ps[t] - v + part[blockIdx.x];
  if(id < NNODES){ off[id] = excl; cur[id] = excl; }
  if(id == 0) off[NNODES] = NEDGES;     // total degree is exactly NEDGES
}

__global__ void scatter_kernel(const int* __restrict__ src, const int* __restrict__ dst,
                               const float* __restrict__ ea, int* __restrict__ cur,
                               int* __restrict__ csr_src, float2* __restrict__ csr_ea){
  int e = blockIdx.x*blockDim.x + threadIdx.x;
  if(e >= NEDGES) return;
  int d = dst[e];
  int p = atomicAdd(&cur[d], 1);
  csr_src[p] = src[e];
  csr_ea[p] = make_float2(ea[2*e], ea[2*e+1]);
}

// ============================ conv0 linear (K=4) ============================
__global__ void gemm_k4(const float* __restrict__ x, const float* __restrict__ W,
                        const float* __restrict__ b, float* __restrict__ out){
  int idx = blockIdx.x*blockDim.x + threadIdx.x;
  if(idx >= NNODES*128) return;
  int r = idx >> 7, c = idx & 127;
  float acc = b[c];
  #pragma unroll
  for(int k=0;k<4;k++) acc += x[r*4+k] * W[k*128+c];
  out[idx] = acc;
}

// ============================ dual GEMM: xl = x@Wa+ba, xr = x@Wb+bb ============================
__launch_bounds__(256)
__global__ void gemm_dual(const float* __restrict__ x,
                          const float* __restrict__ Wa, const float* __restrict__ ba,
                          const float* __restrict__ Wb, const float* __restrict__ bb,
                          float* __restrict__ outa, float* __restrict__ outb, int M){
  __shared__ float xs[64][33];
  __shared__ float wsa[32][128];
  __shared__ float wsb[32][128];
  int tid = threadIdx.x;
  int tc = tid & 31, tr = tid >> 5;
  int row0 = blockIdx.x * 64;
  float acca[8][4], accb[8][4];
  #pragma unroll
  for(int i=0;i<8;i++){
    #pragma unroll
    for(int j=0;j<4;j++){ acca[i][j]=0.f; accb[i][j]=0.f; }
  }
  for(int kb=0;kb<128;kb+=32){
    #pragma unroll
    for(int i=0;i<8;i++){
      int l = tid + i*256;
      int r = l >> 5, k = l & 31;
      int row = row0 + r;
      xs[r][k] = (row < M) ? x[row*128 + kb + k] : 0.f;
    }
    #pragma unroll
    for(int i=0;i<16;i++){
      int l = tid + i*256;
      int k = l >> 7, c = l & 127;
      wsa[k][c] = Wa[(kb+k)*128 + c];
      wsb[k][c] = Wb[(kb+k)*128 + c];
    }
    __syncthreads();
    #pragma unroll 8
    for(int k=0;k<32;k++){
      float xv[8];
      #pragma unroll
      for(int i=0;i<8;i++) xv[i] = xs[tr*8+i][k];
      float4 wa = *(float4*)&wsa[k][tc*4];
      float4 wb = *(float4*)&wsb[k][tc*4];
      #pragma unroll
      for(int i=0;i<8;i++){
        acca[i][0] += xv[i]*wa.x; acca[i][1] += xv[i]*wa.y;
        acca[i][2] += xv[i]*wa.z; acca[i][3] += xv[i]*wa.w;
        accb[i][0] += xv[i]*wb.x; accb[i][1] += xv[i]*wb.y;
        accb[i][2] += xv[i]*wb.z; accb[i][3] += xv[i]*wb.w;
      }
    }
    __syncthreads();
  }
  float4 bva = *(const float4*)&ba[tc*4];
  float4 bvb = *(const float4*)&bb[tc*4];
  #pragma unroll
  for(int i=0;i<8;i++){
    int row = row0 + tr*8 + i;
    if(row < M){
      float4 oa = make_float4(acca[i][0]+bva.x, acca[i][1]+bva.y, acca[i][2]+bva.z, acca[i][3]+bva.w);
      float4 ob = make_float4(accb[i][0]+bvb.x, accb[i][1]+bvb.y, accb[i][2]+bvb.z, accb[i][3]+bvb.w);
      *(float4*)&outa[row*128 + tc*4] = oa;
      *(float4*)&outb[row*128 + tc*4] = ob;
    }
  }
}

// ============================ fused GATv2 edge phase ============================
__launch_bounds__(256)
__global__ void edge_kernel(const float* __restrict__ xl, const float* __restrict__ xr,
                            const int* __restrict__ off, const int* __restrict__ csr_src,
                            const float2* __restrict__ csr_ea,
                            const float* __restrict__ We, const float* __restrict__ att,
                            const float* __restrict__ bias, const float* __restrict__ res,
                            float* __restrict__ out){
  int wid  = (blockIdx.x*blockDim.x + threadIdx.x) >> 6;
  int lane = threadIdx.x & 63;
  if(wid >= NNODES) return;
  int node = wid;
  int c0 = lane*2;
  float2 xr2 = *(const float2*)&xr[node*128 + c0];
  float2 xls = *(const float2*)&xl[node*128 + c0];
  float2 av  = *(const float2*)&att[c0];
  float2 w0  = *(const float2*)&We[c0];
  float2 w1  = *(const float2*)&We[128 + c0];

  float zx = xls.x + xr2.x; zx = zx > 0.f ? zx : 0.2f*zx;
  float zy = xls.y + xr2.y; zy = zy > 0.f ? zy : 0.2f*zy;
  float part = zx*av.x + zy*av.y;
  #pragma unroll
  for(int o=1;o<16;o<<=1) part += __shfl_xor(part, o, 64);
  float m = part;
  float den = 1.f;
  float accx = xls.x, accy = xls.y;

  int e0 = off[node], e1 = off[node+1];
  for(int e=e0;e<e1;e++){
    int s = csr_src[e];
    float2 ea = csr_ea[e];
    float2 xv = *(const float2*)&xl[s*128 + c0];
    float z0 = xv.x + xr2.x + ea.x*w0.x + ea.y*w1.x; z0 = z0 > 0.f ? z0 : 0.2f*z0;
    float z1 = xv.y + xr2.y + ea.x*w0.y + ea.y*w1.y; z1 = z1 > 0.f ? z1 : 0.2f*z1;
    float p = z0*av.x + z1*av.y;
    #pragma unroll
    for(int o=1;o<16;o<<=1) p += __shfl_xor(p, o, 64);
    float nm = fmaxf(m, p);
    float sc = __expf(m - nm);
    float pe = __expf(p - nm);
    den  = den*sc + pe;
    accx = accx*sc + pe*xv.x;
    accy = accy*sc + pe*xv.y;
    m = nm;
  }
  float inv = 1.f/(den + 1e-16f);
  float ox = accx*inv + bias[c0];
  float oy = accy*inv + bias[c0+1];
  ox = ox > 0.f ? ox : 0.f;
  oy = oy > 0.f ? oy : 0.f;
  if(res){ ox += res[node*128 + c0]; oy += res[node*128 + c0 + 1]; }
  *(float2*)&out[node*128 + c0] = make_float2(ox, oy);
}

// ============================ pooling ============================
#define POOL_CHUNK 128
__launch_bounds__(128)
__global__ void pool_kernel(const float* __restrict__ x, const int* __restrict__ batch,
                            float* __restrict__ sums, float* __restrict__ maxv,
                            float* __restrict__ cnt){
  int c = threadIdx.x;
  int n0 = blockIdx.x * POOL_CHUNK;
  if(n0 >= NNODES) return;
  int n1 = n0 + POOL_CHUNK; if(n1 > NNODES) n1 = NNODES;
  int curb = batch[n0];
  float s = 0.f, mx = 0.f;
  float segc = 0.f;
  for(int nd = n0; nd < n1; nd++){
    int b = batch[nd];
    if(b != curb){
      atomicAdd(&sums[curb*128 + c], s);
      atomicMax((int*)&maxv[curb*128 + c], __float_as_int(mx));
      if(c == 0) atomicAdd(&cnt[curb], segc);
      curb = b; s = 0.f; mx = 0.f; segc = 0.f;
    }
    float v = x[nd*128 + c];
    s += v; mx = fmaxf(mx, v); segc += 1.f;
  }
  atomicAdd(&sums[curb*128 + c], s);
  atomicMax((int*)&maxv[curb*128 + c], __float_as_int(mx));
  if(c == 0) atomicAdd(&cnt[curb], segc);
}

__global__ void pool_fin(const float* __restrict__ sums, const float* __restrict__ maxv,
                         const float* __restrict__ cnt, float* __restrict__ X){
  int idx = blockIdx.x*blockDim.x + threadIdx.x;
  if(idx >= NBATCH*128) return;
  int b = idx >> 7, c = idx & 127;
  float ct = cnt[b]; ct = ct > 1.f ? ct : 1.f;
  X[b*256 + c]       = sums[idx] / ct;
  X[b*256 + 128 + c] = maxv[idx];
}

// ============================ dense layers ============================
__global__ void dense_kernel(const float* __restrict__ in, const float* __restrict__ W,
                             const float* __restrict__ b, float* __restrict__ out,
                             int M, int K, int N, int act, int ostride){
  int idx = blockIdx.x*blockDim.x + threadIdx.x;
  if(idx >= M*N) return;
  int r = idx / N, c = idx - r*N;
  float acc = b[c];
  for(int k=0;k<K;k++) acc += in[r*K+k] * W[k*N+c];
  if(act == 1) acc = fmaxf(acc, 0.f);
  else if(act == 2) acc = tanhf(acc);
  out[r*ostride + c] = acc;
}

// ============================ launch ============================
extern "C" void kernel_launch(void* const* d_in, const int* in_sizes, int n_in,
                              void* d_out, int out_size, void* d_ws, size_t ws_size,
                              hipStream_t stream) {
  const float* nodes  = (const float*)d_in[0];
  const int*   eidx   = (const int*)  d_in[1];
  const float* eattr  = (const float*)d_in[2];
  const int*   batch  = (const int*)  d_in[3];
  const float* W0l    = (const float*)d_in[4];
  const float* b0l    = (const float*)d_in[5];
  const float* W0r    = (const float*)d_in[6];
  const float* b0r    = (const float*)d_in[7];
  const float* W0e    = (const float*)d_in[8];
  const float* att0   = (const float*)d_in[9];
  const float* bias0  = (const float*)d_in[10];
  const float* Wl     = (const float*)d_in[11];
  const float* bl     = (const float*)d_in[12];
  const float* Wr     = (const float*)d_in[13];
  const float* br     = (const float*)d_in[14];
  const float* We     = (const float*)d_in[15];
  const float* atts   = (const float*)d_in[16];
  const float* biases = (const float*)d_in[17];
  const float* D1_W   = (const float*)d_in[18];
  const float* D1_b   = (const float*)d_in[19];
  const float* D23_W  = (const float*)d_in[20];
  const float* D23_b  = (const float*)d_in[21];
  const float* H1_W   = (const float*)d_in[22];
  const float* H1_b   = (const float*)d_in[23];
  const float* H2_W   = (const float*)d_in[24];
  const float* H2_b   = (const float*)d_in[25];
  const float* H3_W   = (const float*)d_in[26];
  const float* H3_b   = (const float*)d_in[27];

  // ---- workspace layout ----
  char* ws = (char*)d_ws;
  size_t o = 0;
  auto alloc = [&](size_t bytes)->char*{ char* p = ws + o; o = (o + bytes + 255) & ~(size_t)255; return p; };
  int*    deg     = (int*)   alloc(NNODES*4);
  int*    offs    = (int*)   alloc((NNODES+1)*4);
  int*    cur     = (int*)   alloc(NNODES*4);
  int*    part    = (int*)   alloc(NCHUNK*4);
  int*    csr_src = (int*)   alloc(NEDGES*4);
  float2* csr_ea  = (float2*)alloc(NEDGES*8);
  float*  xl      = (float*) alloc((size_t)NNODES*128*4);
  float*  xr      = (float*) alloc((size_t)NNODES*128*4);
  float*  bufA    = (float*) alloc((size_t)NNODES*128*4);
  float*  bufB    = (float*) alloc((size_t)NNODES*128*4);
  float*  pool    = (float*) alloc((NBATCH*128*2 + NBATCH)*4);
  float*  sums    = pool;
  float*  maxv    = pool + NBATCH*128;
  float*  cnt     = pool + NBATCH*256;
  float*  X       = (float*) alloc(NBATCH*256*4);
  float*  t1      = (float*) alloc(NBATCH*128*4);
  float*  t2      = (float*) alloc(NBATCH*128*4);
  float*  t3      = (float*) alloc(NBATCH*64*4);
  (void)ws_size; (void)in_sizes; (void)n_in; (void)out_size;

  const int* src = eidx;
  const int* dst = eidx + NEDGES;

  // ---- CSR build ----
  hipMemsetAsync(deg, 0, NNODES*4, stream);
  hipMemsetAsync(pool, 0, (NBATCH*128*2 + NBATCH)*4, stream);
  hist_kernel<<<(NEDGES+255)/256, 256, 0, stream>>>(dst, deg);
  deg_partial<<<NCHUNK, SCAN_BLOCK, 0, stream>>>(deg, part);
  part_scan<<<1, 256, 0, stream>>>(part);
  scan_final<<<NCHUNK, SCAN_BLOCK, 0, stream>>>(deg, part, offs, cur);
  scatter_kernel<<<(NEDGES+255)/256, 256, 0, stream>>>(src, dst, eattr, cur, csr_src, csr_ea);

  // ---- conv0 ----
  gemm_k4<<<(NNODES*128+255)/256, 256, 0, stream>>>(nodes, W0l, b0l, xl);
  gemm_k4<<<(NNODES*128+255)/256, 256, 0, stream>>>(nodes, W0r, b0r, xr);
  edge_kernel<<<(NNODES+3)/4, 256, 0, stream>>>(xl, xr, offs, csr_src, csr_ea,
                                                W0e, att0, bias0, nullptr, bufA);

  // ---- 4 skip blocks x 2 convs ----
  const int gemm_grid = (NNODES + 63) / 64;
  for(int blk=0; blk<4; blk++){
    int j = 2*blk;
    gemm_dual<<<gemm_grid, 256, 0, stream>>>(bufA, Wl + (size_t)j*16384, bl + j*128,
                                             Wr + (size_t)j*16384, br + j*128, xl, xr, NNODES);
    edge_kernel<<<(NNODES+3)/4, 256, 0, stream>>>(xl, xr, offs, csr_src, csr_ea,
                                                  We + j*256, atts + j*128, biases + j*128,
                                                  nullptr, bufB);
    j = 2*blk + 1;
    gemm_dual<<<gemm_grid, 256, 0, stream>>>(bufB, Wl + (size_t)j*16384, bl + j*128,
                                             Wr + (size_t)j*16384, br + j*128, xl, xr, NNODES);
    edge_kernel<<<(NNODES+3)/4, 256, 0, stream>>>(xl, xr, offs, csr_src, csr_ea,
                                                  We + j*256, atts + j*128, biases + j*128,
                                                  bufA /*residual*/, bufA);
  }

  // ---- pooling ----
  pool_kernel<<<(NNODES + POOL_CHUNK - 1)/POOL_CHUNK, 128, 0, stream>>>(bufA, batch, sums, maxv, cnt);
  pool_fin<<<(NBATCH*128+255)/256, 256, 0, stream>>>(sums, maxv, cnt, X);

  // ---- dense trunk ----
  dense_kernel<<<(NBATCH*128+255)/256, 256, 0, stream>>>(X,  D1_W,          D1_b,        t1, NBATCH, 256, 128, 1, 128);
  dense_kernel<<<(NBATCH*128+255)/256, 256, 0, stream>>>(t1, D23_W,         D23_b,       t2, NBATCH, 128, 128, 1, 128);
  dense_kernel<<<(NBATCH*128+255)/256, 256, 0, stream>>>(t2, D23_W + 16384, D23_b + 128, t1, NBATCH, 128, 128, 1, 128);

  // ---- 3 heads ----
  for(int h=0; h<3; h++){
    dense_kernel<<<(NBATCH*128+255)/256, 256, 0, stream>>>(t1, H1_W + (size_t)h*16384, H1_b + h*128, t2, NBATCH, 128, 128, 1, 128);
    dense_kernel<<<(NBATCH*64+255)/256, 256, 0, stream>>>(t2, H2_W + (size_t)h*8192,  H2_b + h*64,  t3, NBATCH, 128, 64, 1, 64);
    dense_kernel<<<1, 64, 0, stream>>>(t3, H3_W + (size_t)h*64, H3_b + h, (float*)d_out + h, NBATCH, 64, 1, (h==0)?2:0, 3);
  }
}

// Round 4
// 1799.636 us; speedup vs baseline: 1.4033x; 1.1036x over previous
//
#include <hip/hip_runtime.h>
#include <cmath>

#define NNODES 50000
#define NEDGES 600000
#define NBATCH 50
#define SCAN_BLOCK 256
#define NCHUNK ((NNODES + SCAN_BLOCK - 1) / SCAN_BLOCK)   // 196

// ============================ CSR build ============================
__global__ void hist_kernel(const int* __restrict__ dst, int* __restrict__ deg){
  int e = blockIdx.x*blockDim.x + threadIdx.x;
  if(e < NEDGES) atomicAdd(&deg[dst[e]], 1);
}

__global__ void deg_partial(const int* __restrict__ deg, int* __restrict__ part){
  __shared__ int red[SCAN_BLOCK];
  int t = threadIdx.x, id = blockIdx.x*SCAN_BLOCK + t;
  red[t] = (id < NNODES) ? deg[id] : 0;
  __syncthreads();
  for(int o = SCAN_BLOCK/2; o > 0; o >>= 1){
    if(t < o) red[t] += red[t+o];
    __syncthreads();
  }
  if(t == 0) part[blockIdx.x] = red[0];
}

__global__ void part_scan(int* __restrict__ part){
  __shared__ int ps[256];
  int t = threadIdx.x;
  int v = (t < NCHUNK) ? part[t] : 0;
  ps[t] = v; __syncthreads();
  for(int o=1;o<256;o<<=1){
    int u = (t>=o) ? ps[t-o] : 0;
    __syncthreads();
    ps[t] += u;
    __syncthreads();
  }
  if(t < NCHUNK) part[t] = ps[t] - v;   // exclusive
}

__global__ void scan_final(const int* __restrict__ deg, const int* __restrict__ part,
                           int* __restrict__ off, int* __restrict__ cur){
  __shared__ int ps[SCAN_BLOCK];
  int t = threadIdx.x, id = blockIdx.x*SCAN_BLOCK + t;
  int v = (id < NNODES) ? deg[id] : 0;
  ps[t] = v; __syncthreads();
  for(int o=1;o<SCAN_BLOCK;o<<=1){
    int u = (t>=o) ? ps[t-o] : 0;
    __syncthreads();
    ps[t] += u;
    __syncthreads();
  }
  int excl = ps[t] - v + part[blockIdx.x];
  if(id < NNODES){ off[id] = excl; cur[id] = excl; }
  if(id == 0) off[NNODES] = NEDGES;
}

__global__ void scatter_kernel(const int* __restrict__ src, const int* __restrict__ dst,
                               const float* __restrict__ ea, int* __restrict__ cur,
                               int* __restrict__ csr_src, float2* __restrict__ csr_ea){
  int e = blockIdx.x*blockDim.x + threadIdx.x;
  if(e >= NEDGES) return;
  int d = dst[e];
  int p = atomicAdd(&cur[d], 1);
  csr_src[p] = src[e];
  csr_ea[p] = make_float2(ea[2*e], ea[2*e+1]);
}

// ============================ conv0 linear (K=4), both outputs ============================
__global__ void gemm_k4_dual(const float* __restrict__ x,
                             const float* __restrict__ Wa, const float* __restrict__ ba,
                             const float* __restrict__ Wb, const float* __restrict__ bb,
                             float* __restrict__ outa, float* __restrict__ outb){
  int idx = blockIdx.x*blockDim.x + threadIdx.x;
  if(idx >= NNODES*128) return;
  int r = idx >> 7, c = idx & 127;
  float4 xv = *(const float4*)&x[r*4];
  float acca = ba[c] + xv.x*Wa[c] + xv.y*Wa[128+c] + xv.z*Wa[256+c] + xv.w*Wa[384+c];
  float accb = bb[c] + xv.x*Wb[c] + xv.y*Wb[128+c] + xv.z*Wb[256+c] + xv.w*Wb[384+c];
  outa[idx] = acca;
  outb[idx] = accb;
}

// ============================ dual GEMM: xl = x@Wa+ba, xr = x@Wb+bb ============================
__launch_bounds__(256)
__global__ void gemm_dual(const float* __restrict__ x,
                          const float* __restrict__ Wa, const float* __restrict__ ba,
                          const float* __restrict__ Wb, const float* __restrict__ bb,
                          float* __restrict__ outa, float* __restrict__ outb, int M){
  __shared__ float xs[64][33];
  __shared__ float wsa[32][128];
  __shared__ float wsb[32][128];
  int tid = threadIdx.x;
  int tc = tid & 31, tr = tid >> 5;
  int row0 = blockIdx.x * 64;
  float acca[8][4], accb[8][4];
  #pragma unroll
  for(int i=0;i<8;i++){
    #pragma unroll
    for(int j=0;j<4;j++){ acca[i][j]=0.f; accb[i][j]=0.f; }
  }
  for(int kb=0;kb<128;kb+=32){
    #pragma unroll
    for(int i=0;i<8;i++){
      int l = tid + i*256;
      int r = l >> 5, k = l & 31;
      int row = row0 + r;
      xs[r][k] = (row < M) ? x[row*128 + kb + k] : 0.f;
    }
    #pragma unroll
    for(int i=0;i<16;i++){
      int l = tid + i*256;
      int k = l >> 7, c = l & 127;
      wsa[k][c] = Wa[(kb+k)*128 + c];
      wsb[k][c] = Wb[(kb+k)*128 + c];
    }
    __syncthreads();
    #pragma unroll 8
    for(int k=0;k<32;k++){
      float xv[8];
      #pragma unroll
      for(int i=0;i<8;i++) xv[i] = xs[tr*8+i][k];
      float4 wa = *(float4*)&wsa[k][tc*4];
      float4 wb = *(float4*)&wsb[k][tc*4];
      #pragma unroll
      for(int i=0;i<8;i++){
        acca[i][0] += xv[i]*wa.x; acca[i][1] += xv[i]*wa.y;
        acca[i][2] += xv[i]*wa.z; acca[i][3] += xv[i]*wa.w;
        accb[i][0] += xv[i]*wb.x; accb[i][1] += xv[i]*wb.y;
        accb[i][2] += xv[i]*wb.z; accb[i][3] += xv[i]*wb.w;
      }
    }
    __syncthreads();
  }
  float4 bva = *(const float4*)&ba[tc*4];
  float4 bvb = *(const float4*)&bb[tc*4];
  #pragma unroll
  for(int i=0;i<8;i++){
    int row = row0 + tr*8 + i;
    if(row < M){
      float4 oa = make_float4(acca[i][0]+bva.x, acca[i][1]+bva.y, acca[i][2]+bva.z, acca[i][3]+bva.w);
      float4 ob = make_float4(accb[i][0]+bvb.x, accb[i][1]+bvb.y, accb[i][2]+bvb.z, accb[i][3]+bvb.w);
      *(float4*)&outa[row*128 + tc*4] = oa;
      *(float4*)&outb[row*128 + tc*4] = ob;
    }
  }
}

// ============================ fused GATv2 edge phase ============================
// One wave per destination node; lane l owns channels 2l,2l+1; 16-lane groups = heads.
// 4 edges per iteration: independent gathers + interleaved shuffle chains, one
// merged online-softmax update (5 exp / 4 edges). Tail masked with p=-1e30.
__launch_bounds__(256)
__global__ void edge_kernel(const float* __restrict__ xl, const float* __restrict__ xr,
                            const int* __restrict__ off, const int* __restrict__ csr_src,
                            const float2* __restrict__ csr_ea,
                            const float* __restrict__ We, const float* __restrict__ att,
                            const float* __restrict__ bias, const float* __restrict__ res,
                            float* __restrict__ out){
  int wid  = (blockIdx.x*blockDim.x + threadIdx.x) >> 6;
  int lane = threadIdx.x & 63;
  if(wid >= NNODES) return;
  int node = wid;
  int c0 = lane*2;
  float2 xr2 = *(const float2*)&xr[node*128 + c0];
  float2 xls = *(const float2*)&xl[node*128 + c0];
  float2 av  = *(const float2*)&att[c0];
  float2 w0  = *(const float2*)&We[c0];
  float2 w1  = *(const float2*)&We[128 + c0];

  // self-loop (src=node, ea=0)
  float zx = xls.x + xr2.x; zx = zx > 0.f ? zx : 0.2f*zx;
  float zy = xls.y + xr2.y; zy = zy > 0.f ? zy : 0.2f*zy;
  float m = zx*av.x + zy*av.y;
  #pragma unroll
  for(int o=1;o<16;o<<=1) m += __shfl_xor(m, o, 64);
  float den = 1.f;
  float accx = xls.x, accy = xls.y;

  int e0 = off[node], e1 = off[node+1];
  for(int e=e0; e<e1; e+=4){
    int cnt = e1 - e;                       // wave-uniform
    int   s[4];
    float2 ea[4];
    #pragma unroll
    for(int j=0;j<4;j++){
      if(j < cnt){ s[j] = csr_src[e+j]; ea[j] = csr_ea[e+j]; }
      else       { s[j] = node;         ea[j] = make_float2(0.f,0.f); }
    }
    float2 xv[4];
    #pragma unroll
    for(int j=0;j<4;j++) xv[j] = *(const float2*)&xl[(size_t)s[j]*128 + c0];
    float p[4];
    #pragma unroll
    for(int j=0;j<4;j++){
      float z0 = xv[j].x + xr2.x + ea[j].x*w0.x + ea[j].y*w1.x; z0 = z0 > 0.f ? z0 : 0.2f*z0;
      float z1 = xv[j].y + xr2.y + ea[j].x*w0.y + ea[j].y*w1.y; z1 = z1 > 0.f ? z1 : 0.2f*z1;
      p[j] = z0*av.x + z1*av.y;
    }
    #pragma unroll
    for(int o=1;o<16;o<<=1){
      #pragma unroll
      for(int j=0;j<4;j++) p[j] += __shfl_xor(p[j], o, 64);
    }
    #pragma unroll
    for(int j=0;j<4;j++) if(j >= cnt) p[j] = -1e30f;
    float nm = m;
    #pragma unroll
    for(int j=0;j<4;j++) nm = fmaxf(nm, p[j]);
    float sc = __expf(m - nm);
    float pe[4];
    #pragma unroll
    for(int j=0;j<4;j++) pe[j] = __expf(p[j] - nm);
    den  = den*sc  + pe[0]+pe[1]+pe[2]+pe[3];
    accx = accx*sc + pe[0]*xv[0].x + pe[1]*xv[1].x + pe[2]*xv[2].x + pe[3]*xv[3].x;
    accy = accy*sc + pe[0]*xv[0].y + pe[1]*xv[1].y + pe[2]*xv[2].y + pe[3]*xv[3].y;
    m = nm;
  }
  float inv = 1.f/(den + 1e-16f);
  float ox = accx*inv + bias[c0];
  float oy = accy*inv + bias[c0+1];
  ox = ox > 0.f ? ox : 0.f;
  oy = oy > 0.f ? oy : 0.f;
  if(res){ ox += res[node*128 + c0]; oy += res[node*128 + c0 + 1]; }
  *(float2*)&out[node*128 + c0] = make_float2(ox, oy);
}

// ============================ pooling ============================
#define POOL_CHUNK 128
__launch_bounds__(128)
__global__ void pool_kernel(const float* __restrict__ x, const int* __restrict__ batch,
                            float* __restrict__ sums, float* __restrict__ maxv,
                            float* __restrict__ cnt){
  int c = threadIdx.x;
  int n0 = blockIdx.x * POOL_CHUNK;
  if(n0 >= NNODES) return;
  int n1 = n0 + POOL_CHUNK; if(n1 > NNODES) n1 = NNODES;
  int curb = batch[n0];
  float s = 0.f, mx = 0.f;
  float segc = 0.f;
  for(int nd = n0; nd < n1; nd++){
    int b = batch[nd];
    if(b != curb){
      atomicAdd(&sums[curb*128 + c], s);
      atomicMax((int*)&maxv[curb*128 + c], __float_as_int(mx));
      if(c == 0) atomicAdd(&cnt[curb], segc);
      curb = b; s = 0.f; mx = 0.f; segc = 0.f;
    }
    float v = x[nd*128 + c];
    s += v; mx = fmaxf(mx, v); segc += 1.f;
  }
  atomicAdd(&sums[curb*128 + c], s);
  atomicMax((int*)&maxv[curb*128 + c], __float_as_int(mx));
  if(c == 0) atomicAdd(&cnt[curb], segc);
}

__global__ void pool_fin(const float* __restrict__ sums, const float* __restrict__ maxv,
                         const float* __restrict__ cnt, float* __restrict__ X){
  int idx = blockIdx.x*blockDim.x + threadIdx.x;
  if(idx >= NBATCH*128) return;
  int b = idx >> 7, c = idx & 127;
  float ct = cnt[b]; ct = ct > 1.f ? ct : 1.f;
  X[b*256 + c]       = sums[idx] / ct;
  X[b*256 + 128 + c] = maxv[idx];
}

// ============================ dense layers ============================
__global__ void dense_kernel(const float* __restrict__ in, const float* __restrict__ W,
                             const float* __restrict__ b, float* __restrict__ out,
                             int M, int K, int N, int act, int ostride){
  int idx = blockIdx.x*blockDim.x + threadIdx.x;
  if(idx >= M*N) return;
  int r = idx / N, c = idx - r*N;
  float acc = b[c];
  for(int k=0;k<K;k++) acc += in[r*K+k] * W[k*N+c];
  if(act == 1) acc = fmaxf(acc, 0.f);
  else if(act == 2) acc = tanhf(acc);
  out[r*ostride + c] = acc;
}

// ============================ launch ============================
extern "C" void kernel_launch(void* const* d_in, const int* in_sizes, int n_in,
                              void* d_out, int out_size, void* d_ws, size_t ws_size,
                              hipStream_t stream) {
  const float* nodes  = (const float*)d_in[0];
  const int*   eidx   = (const int*)  d_in[1];
  const float* eattr  = (const float*)d_in[2];
  const int*   batch  = (const int*)  d_in[3];
  const float* W0l    = (const float*)d_in[4];
  const float* b0l    = (const float*)d_in[5];
  const float* W0r    = (const float*)d_in[6];
  const float* b0r    = (const float*)d_in[7];
  const float* W0e    = (const float*)d_in[8];
  const float* att0   = (const float*)d_in[9];
  const float* bias0  = (const float*)d_in[10];
  const float* Wl     = (const float*)d_in[11];
  const float* bl     = (const float*)d_in[12];
  const float* Wr     = (const float*)d_in[13];
  const float* br     = (const float*)d_in[14];
  const float* We     = (const float*)d_in[15];
  const float* atts   = (const float*)d_in[16];
  const float* biases = (const float*)d_in[17];
  const float* D1_W   = (const float*)d_in[18];
  const float* D1_b   = (const float*)d_in[19];
  const float* D23_W  = (const float*)d_in[20];
  const float* D23_b  = (const float*)d_in[21];
  const float* H1_W   = (const float*)d_in[22];
  const float* H1_b   = (const float*)d_in[23];
  const float* H2_W   = (const float*)d_in[24];
  const float* H2_b   = (const float*)d_in[25];
  const float* H3_W   = (const float*)d_in[26];
  const float* H3_b   = (const float*)d_in[27];

  // ---- workspace layout ----
  char* ws = (char*)d_ws;
  size_t o = 0;
  auto alloc = [&](size_t bytes)->char*{ char* p = ws + o; o = (o + bytes + 255) & ~(size_t)255; return p; };
  int*    deg     = (int*)   alloc(NNODES*4);
  int*    offs    = (int*)   alloc((NNODES+1)*4);
  int*    cur     = (int*)   alloc(NNODES*4);
  int*    part    = (int*)   alloc(NCHUNK*4);
  int*    csr_src = (int*)   alloc(NEDGES*4);
  float2* csr_ea  = (float2*)alloc(NEDGES*8);
  float*  xl      = (float*) alloc((size_t)NNODES*128*4);
  float*  xr      = (float*) alloc((size_t)NNODES*128*4);
  float*  bufA    = (float*) alloc((size_t)NNODES*128*4);
  float*  bufB    = (float*) alloc((size_t)NNODES*128*4);
  float*  pool    = (float*) alloc((NBATCH*128*2 + NBATCH)*4);
  float*  sums    = pool;
  float*  maxv    = pool + NBATCH*128;
  float*  cnt     = pool + NBATCH*256;
  float*  X       = (float*) alloc(NBATCH*256*4);
  float*  t1      = (float*) alloc(NBATCH*128*4);
  float*  t2      = (float*) alloc(NBATCH*128*4);
  float*  t3      = (float*) alloc(NBATCH*64*4);
  (void)ws_size; (void)in_sizes; (void)n_in; (void)out_size;

  const int* src = eidx;
  const int* dst = eidx + NEDGES;

  // ---- CSR build ----
  hipMemsetAsync(deg, 0, NNODES*4, stream);
  hipMemsetAsync(pool, 0, (NBATCH*128*2 + NBATCH)*4, stream);
  hist_kernel<<<(NEDGES+255)/256, 256, 0, stream>>>(dst, deg);
  deg_partial<<<NCHUNK, SCAN_BLOCK, 0, stream>>>(deg, part);
  part_scan<<<1, 256, 0, stream>>>(part);
  scan_final<<<NCHUNK, SCAN_BLOCK, 0, stream>>>(deg, part, offs, cur);
  scatter_kernel<<<(NEDGES+255)/256, 256, 0, stream>>>(src, dst, eattr, cur, csr_src, csr_ea);

  // ---- conv0 ----
  gemm_k4_dual<<<(NNODES*128+255)/256, 256, 0, stream>>>(nodes, W0l, b0l, W0r, b0r, xl, xr);
  edge_kernel<<<(NNODES+3)/4, 256, 0, stream>>>(xl, xr, offs, csr_src, csr_ea,
                                                W0e, att0, bias0, nullptr, bufA);

  // ---- 4 skip blocks x 2 convs ----
  const int gemm_grid = (NNODES + 63) / 64;
  for(int blk=0; blk<4; blk++){
    int j = 2*blk;
    gemm_dual<<<gemm_grid, 256, 0, stream>>>(bufA, Wl + (size_t)j*16384, bl + j*128,
                                             Wr + (size_t)j*16384, br + j*128, xl, xr, NNODES);
    edge_kernel<<<(NNODES+3)/4, 256, 0, stream>>>(xl, xr, offs, csr_src, csr_ea,
                                                  We + j*256, atts + j*128, biases + j*128,
                                                  nullptr, bufB);
    j = 2*blk + 1;
    gemm_dual<<<gemm_grid, 256, 0, stream>>>(bufB, Wl + (size_t)j*16384, bl + j*128,
                                             Wr + (size_t)j*16384, br + j*128, xl, xr, NNODES);
    edge_kernel<<<(NNODES+3)/4, 256, 0, stream>>>(xl, xr, offs, csr_src, csr_ea,
                                                  We + j*256, atts + j*128, biases + j*128,
                                                  bufA /*residual*/, bufA);
  }

  // ---- pooling ----
  pool_kernel<<<(NNODES + POOL_CHUNK - 1)/POOL_CHUNK, 128, 0, stream>>>(bufA, batch, sums, maxv, cnt);
  pool_fin<<<(NBATCH*128+255)/256, 256, 0, stream>>>(sums, maxv, cnt, X);

  // ---- dense trunk ----
  dense_kernel<<<(NBATCH*128+255)/256, 256, 0, stream>>>(X,  D1_W,          D1_b,        t1, NBATCH, 256, 128, 1, 128);
  dense_kernel<<<(NBATCH*128+255)/256, 256, 0, stream>>>(t1, D23_W,         D23_b,       t2, NBATCH, 128, 128, 1, 128);
  dense_kernel<<<(NBATCH*128+255)/256, 256, 0, stream>>>(t2, D23_W + 16384, D23_b + 128, t1, NBATCH, 128, 128, 1, 128);

  // ---- 3 heads ----
  for(int h=0; h<3; h++){
    dense_kernel<<<(NBATCH*128+255)/256, 256, 0, stream>>>(t1, H1_W + (size_t)h*16384, H1_b + h*128, t2, NBATCH, 128, 128, 1, 128);
    dense_kernel<<<(NBATCH*64+255)/256, 256, 0, stream>>>(t2, H2_W + (size_t)h*8192,  H2_b + h*64,  t3, NBATCH, 128, 64, 1, 64);
    dense_kernel<<<1, 64, 0, stream>>>(t3, H3_W + (size_t)h*64, H3_b + h, (float*)d_out + h, NBATCH, 64, 1, (h==0)?2:0, 3);
  }
}

// Round 5
// 1559.223 us; speedup vs baseline: 1.6197x; 1.1542x over previous
//
#include <hip/hip_runtime.h>
#include <cmath>

#define NNODES 50000
#define NEDGES 600000
#define NBATCH 50
#define SCAN_BLOCK 256
#define NCHUNK ((NNODES + SCAN_BLOCK - 1) / SCAN_BLOCK)   // 196

// ============================ CSR build ============================
__global__ void hist_kernel(const int* __restrict__ dst, int* __restrict__ deg){
  int e = blockIdx.x*blockDim.x + threadIdx.x;
  if(e < NEDGES) atomicAdd(&deg[dst[e]], 1);
}

__global__ void deg_partial(const int* __restrict__ deg, int* __restrict__ part){
  __shared__ int red[SCAN_BLOCK];
  int t = threadIdx.x, id = blockIdx.x*SCAN_BLOCK + t;
  red[t] = (id < NNODES) ? deg[id] : 0;
  __syncthreads();
  for(int o = SCAN_BLOCK/2; o > 0; o >>= 1){
    if(t < o) red[t] += red[t+o];
    __syncthreads();
  }
  if(t == 0) part[blockIdx.x] = red[0];
}

__global__ void part_scan(int* __restrict__ part){
  __shared__ int ps[256];
  int t = threadIdx.x;
  int v = (t < NCHUNK) ? part[t] : 0;
  ps[t] = v; __syncthreads();
  for(int o=1;o<256;o<<=1){
    int u = (t>=o) ? ps[t-o] : 0;
    __syncthreads();
    ps[t] += u;
    __syncthreads();
  }
  if(t < NCHUNK) part[t] = ps[t] - v;   // exclusive
}

__global__ void scan_final(const int* __restrict__ deg, const int* __restrict__ part,
                           int* __restrict__ off, int* __restrict__ cur){
  __shared__ int ps[SCAN_BLOCK];
  int t = threadIdx.x, id = blockIdx.x*SCAN_BLOCK + t;
  int v = (id < NNODES) ? deg[id] : 0;
  ps[t] = v; __syncthreads();
  for(int o=1;o<SCAN_BLOCK;o<<=1){
    int u = (t>=o) ? ps[t-o] : 0;
    __syncthreads();
    ps[t] += u;
    __syncthreads();
  }
  int excl = ps[t] - v + part[blockIdx.x];
  if(id < NNODES){ off[id] = excl; cur[id] = excl; }
  if(id == 0) off[NNODES] = NEDGES;
}

__global__ void scatter_kernel(const int* __restrict__ src, const int* __restrict__ dst,
                               const float* __restrict__ ea, int* __restrict__ cur,
                               int* __restrict__ csr_src, float2* __restrict__ csr_ea){
  int e = blockIdx.x*blockDim.x + threadIdx.x;
  if(e >= NEDGES) return;
  int d = dst[e];
  int p = atomicAdd(&cur[d], 1);
  csr_src[p] = src[e];
  csr_ea[p] = make_float2(ea[2*e], ea[2*e+1]);
}

// ============================ conv0 linear (K=4), both outputs ============================
__global__ void gemm_k4_dual(const float* __restrict__ x,
                             const float* __restrict__ Wa, const float* __restrict__ ba,
                             const float* __restrict__ Wb, const float* __restrict__ bb,
                             float* __restrict__ outa, float* __restrict__ outb){
  int idx = blockIdx.x*blockDim.x + threadIdx.x;
  if(idx >= NNODES*128) return;
  int r = idx >> 7, c = idx & 127;
  float4 xv = *(const float4*)&x[r*4];
  float acca = ba[c] + xv.x*Wa[c] + xv.y*Wa[128+c] + xv.z*Wa[256+c] + xv.w*Wa[384+c];
  float accb = bb[c] + xv.x*Wb[c] + xv.y*Wb[128+c] + xv.z*Wb[256+c] + xv.w*Wb[384+c];
  outa[idx] = acca;
  outb[idx] = accb;
}

// ============================ dual GEMM: xl = x@Wa+ba, xr = x@Wb+bb ============================
__launch_bounds__(256)
__global__ void gemm_dual(const float* __restrict__ x,
                          const float* __restrict__ Wa, const float* __restrict__ ba,
                          const float* __restrict__ Wb, const float* __restrict__ bb,
                          float* __restrict__ outa, float* __restrict__ outb, int M){
  __shared__ float xs[64][33];
  __shared__ float wsa[32][128];
  __shared__ float wsb[32][128];
  int tid = threadIdx.x;
  int tc = tid & 31, tr = tid >> 5;
  int row0 = blockIdx.x * 64;
  float acca[8][4], accb[8][4];
  #pragma unroll
  for(int i=0;i<8;i++){
    #pragma unroll
    for(int j=0;j<4;j++){ acca[i][j]=0.f; accb[i][j]=0.f; }
  }
  for(int kb=0;kb<128;kb+=32){
    #pragma unroll
    for(int i=0;i<8;i++){
      int l = tid + i*256;
      int r = l >> 5, k = l & 31;
      int row = row0 + r;
      xs[r][k] = (row < M) ? x[row*128 + kb + k] : 0.f;
    }
    #pragma unroll
    for(int i=0;i<16;i++){
      int l = tid + i*256;
      int k = l >> 7, c = l & 127;
      wsa[k][c] = Wa[(kb+k)*128 + c];
      wsb[k][c] = Wb[(kb+k)*128 + c];
    }
    __syncthreads();
    #pragma unroll 8
    for(int k=0;k<32;k++){
      float xv[8];
      #pragma unroll
      for(int i=0;i<8;i++) xv[i] = xs[tr*8+i][k];
      float4 wa = *(float4*)&wsa[k][tc*4];
      float4 wb = *(float4*)&wsb[k][tc*4];
      #pragma unroll
      for(int i=0;i<8;i++){
        acca[i][0] += xv[i]*wa.x; acca[i][1] += xv[i]*wa.y;
        acca[i][2] += xv[i]*wa.z; acca[i][3] += xv[i]*wa.w;
        accb[i][0] += xv[i]*wb.x; accb[i][1] += xv[i]*wb.y;
        accb[i][2] += xv[i]*wb.z; accb[i][3] += xv[i]*wb.w;
      }
    }
    __syncthreads();
  }
  float4 bva = *(const float4*)&ba[tc*4];
  float4 bvb = *(const float4*)&bb[tc*4];
  #pragma unroll
  for(int i=0;i<8;i++){
    int row = row0 + tr*8 + i;
    if(row < M){
      float4 oa = make_float4(acca[i][0]+bva.x, acca[i][1]+bva.y, acca[i][2]+bva.z, acca[i][3]+bva.w);
      float4 ob = make_float4(accb[i][0]+bvb.x, accb[i][1]+bvb.y, accb[i][2]+bvb.z, accb[i][3]+bvb.w);
      *(float4*)&outa[row*128 + tc*4] = oa;
      *(float4*)&outb[row*128 + tc*4] = ob;
    }
  }
}

// ============================ fused GATv2 edge phase ============================
// One wave per destination node; lane l owns channels 2l,2l+1; 16-lane groups = heads.
// 8 edges per iteration: independent gathers + interleaved shuffle chains, one
// merged online-softmax update (9 exp / 8 edges). Tail pads gather node's own
// row (L1-hot) and mask with p=-1e30.
__launch_bounds__(256)
__global__ void edge_kernel(const float* __restrict__ xl, const float* __restrict__ xr,
                            const int* __restrict__ off, const int* __restrict__ csr_src,
                            const float2* __restrict__ csr_ea,
                            const float* __restrict__ We, const float* __restrict__ att,
                            const float* __restrict__ bias, const float* __restrict__ res,
                            float* __restrict__ out){
  int wid  = (blockIdx.x*blockDim.x + threadIdx.x) >> 6;
  int lane = threadIdx.x & 63;
  if(wid >= NNODES) return;
  int node = wid;
  int c0 = lane*2;
  float2 xr2 = *(const float2*)&xr[node*128 + c0];
  float2 xls = *(const float2*)&xl[node*128 + c0];
  float2 av  = *(const float2*)&att[c0];
  float2 w0  = *(const float2*)&We[c0];
  float2 w1  = *(const float2*)&We[128 + c0];

  // self-loop (src=node, ea=0)
  float zx = xls.x + xr2.x; zx = zx > 0.f ? zx : 0.2f*zx;
  float zy = xls.y + xr2.y; zy = zy > 0.f ? zy : 0.2f*zy;
  float m = zx*av.x + zy*av.y;
  #pragma unroll
  for(int o=1;o<16;o<<=1) m += __shfl_xor(m, o, 64);
  float den = 1.f;
  float accx = xls.x, accy = xls.y;

  int e0 = off[node], e1 = off[node+1];
  for(int e=e0; e<e1; e+=8){
    int cnt = e1 - e;                       // wave-uniform
    int   s[8];
    float2 ea[8];
    #pragma unroll
    for(int j=0;j<8;j++){
      if(j < cnt){ s[j] = csr_src[e+j]; ea[j] = csr_ea[e+j]; }
      else       { s[j] = node;         ea[j] = make_float2(0.f,0.f); }
    }
    float2 xv[8];
    #pragma unroll
    for(int j=0;j<8;j++) xv[j] = *(const float2*)&xl[(size_t)s[j]*128 + c0];
    float p[8];
    #pragma unroll
    for(int j=0;j<8;j++){
      float z0 = xv[j].x + xr2.x + ea[j].x*w0.x + ea[j].y*w1.x; z0 = z0 > 0.f ? z0 : 0.2f*z0;
      float z1 = xv[j].y + xr2.y + ea[j].x*w0.y + ea[j].y*w1.y; z1 = z1 > 0.f ? z1 : 0.2f*z1;
      p[j] = z0*av.x + z1*av.y;
    }
    #pragma unroll
    for(int o=1;o<16;o<<=1){
      #pragma unroll
      for(int j=0;j<8;j++) p[j] += __shfl_xor(p[j], o, 64);
    }
    #pragma unroll
    for(int j=0;j<8;j++) if(j >= cnt) p[j] = -1e30f;
    float nm = m;
    #pragma unroll
    for(int j=0;j<8;j++) nm = fmaxf(nm, p[j]);
    float sc = __expf(m - nm);
    float pe[8];
    #pragma unroll
    for(int j=0;j<8;j++) pe[j] = __expf(p[j] - nm);
    float dsum = 0.f, axs = 0.f, ays = 0.f;
    #pragma unroll
    for(int j=0;j<8;j++){
      dsum += pe[j];
      axs  += pe[j]*xv[j].x;
      ays  += pe[j]*xv[j].y;
    }
    den  = den*sc  + dsum;
    accx = accx*sc + axs;
    accy = accy*sc + ays;
    m = nm;
  }
  float inv = 1.f/(den + 1e-16f);
  float ox = accx*inv + bias[c0];
  float oy = accy*inv + bias[c0+1];
  ox = ox > 0.f ? ox : 0.f;
  oy = oy > 0.f ? oy : 0.f;
  if(res){ ox += res[node*128 + c0]; oy += res[node*128 + c0 + 1]; }
  *(float2*)&out[node*128 + c0] = make_float2(ox, oy);
}

// ============================ pooling ============================
#define POOL_CHUNK 128
__launch_bounds__(128)
__global__ void pool_kernel(const float* __restrict__ x, const int* __restrict__ batch,
                            float* __restrict__ sums, float* __restrict__ maxv,
                            float* __restrict__ cnt){
  int c = threadIdx.x;
  int n0 = blockIdx.x * POOL_CHUNK;
  if(n0 >= NNODES) return;
  int n1 = n0 + POOL_CHUNK; if(n1 > NNODES) n1 = NNODES;
  int curb = batch[n0];
  float s = 0.f, mx = 0.f;
  float segc = 0.f;
  for(int nd = n0; nd < n1; nd++){
    int b = batch[nd];
    if(b != curb){
      atomicAdd(&sums[curb*128 + c], s);
      atomicMax((int*)&maxv[curb*128 + c], __float_as_int(mx));
      if(c == 0) atomicAdd(&cnt[curb], segc);
      curb = b; s = 0.f; mx = 0.f; segc = 0.f;
    }
    float v = x[nd*128 + c];
    s += v; mx = fmaxf(mx, v); segc += 1.f;
  }
  atomicAdd(&sums[curb*128 + c], s);
  atomicMax((int*)&maxv[curb*128 + c], __float_as_int(mx));
  if(c == 0) atomicAdd(&cnt[curb], segc);
}

// ============================ fused dense trunk + heads ============================
// One block per batch row (50 blocks, 128 threads). All K compile-time ->
// unrolled, ~16 loads in flight. Replaces pool_fin + 12 dense dispatches.
__launch_bounds__(128)
__global__ void fused_dense(const float* __restrict__ sums, const float* __restrict__ maxv,
                            const float* __restrict__ cnt,
                            const float* __restrict__ D1_W, const float* __restrict__ D1_b,
                            const float* __restrict__ D23_W, const float* __restrict__ D23_b,
                            const float* __restrict__ H1_W, const float* __restrict__ H1_b,
                            const float* __restrict__ H2_W, const float* __restrict__ H2_b,
                            const float* __restrict__ H3_W, const float* __restrict__ H3_b,
                            float* __restrict__ out){
  __shared__ float X[256];
  __shared__ float y[128];
  __shared__ float z[128];
  int b = blockIdx.x, t = threadIdx.x;
  float ct = cnt[b]; ct = ct > 1.f ? ct : 1.f;
  X[t]       = sums[b*128 + t] / ct;
  X[128 + t] = maxv[b*128 + t];
  __syncthreads();
  // D1: 256 -> 128, relu
  float acc = D1_b[t];
  #pragma unroll 16
  for(int k=0;k<256;k++) acc += X[k]*D1_W[k*128+t];
  y[t] = fmaxf(acc, 0.f);
  __syncthreads();
  // D2: 128 -> 128, relu
  acc = D23_b[t];
  #pragma unroll 16
  for(int k=0;k<128;k++) acc += y[k]*D23_W[k*128+t];
  z[t] = fmaxf(acc, 0.f);
  __syncthreads();
  // D3: 128 -> 128, relu
  acc = D23_b[128+t];
  #pragma unroll 16
  for(int k=0;k<128;k++) acc += z[k]*D23_W[16384 + k*128+t];
  y[t] = fmaxf(acc, 0.f);
  __syncthreads();
  // heads
  for(int h=0;h<3;h++){
    acc = H1_b[h*128+t];
    #pragma unroll 16
    for(int k=0;k<128;k++) acc += y[k]*H1_W[h*16384 + k*128+t];
    z[t] = fmaxf(acc, 0.f);
    __syncthreads();
    float v = 0.f;
    if(t < 64){
      float a2 = H2_b[h*64+t];
      #pragma unroll 16
      for(int k=0;k<128;k++) a2 += z[k]*H2_W[h*8192 + k*64+t];
      a2 = fmaxf(a2, 0.f);
      v = a2 * H3_W[h*64 + t];
    }
    #pragma unroll
    for(int o=1;o<64;o<<=1) v += __shfl_xor(v, o, 64);
    if(t == 0){
      float r = v + H3_b[h];
      if(h == 0) r = tanhf(r);
      out[b*3 + h] = r;
    }
    __syncthreads();
  }
}

// ============================ launch ============================
extern "C" void kernel_launch(void* const* d_in, const int* in_sizes, int n_in,
                              void* d_out, int out_size, void* d_ws, size_t ws_size,
                              hipStream_t stream) {
  const float* nodes  = (const float*)d_in[0];
  const int*   eidx   = (const int*)  d_in[1];
  const float* eattr  = (const float*)d_in[2];
  const int*   batch  = (const int*)  d_in[3];
  const float* W0l    = (const float*)d_in[4];
  const float* b0l    = (const float*)d_in[5];
  const float* W0r    = (const float*)d_in[6];
  const float* b0r    = (const float*)d_in[7];
  const float* W0e    = (const float*)d_in[8];
  const float* att0   = (const float*)d_in[9];
  const float* bias0  = (const float*)d_in[10];
  const float* Wl     = (const float*)d_in[11];
  const float* bl     = (const float*)d_in[12];
  const float* Wr     = (const float*)d_in[13];
  const float* br     = (const float*)d_in[14];
  const float* We     = (const float*)d_in[15];
  const float* atts   = (const float*)d_in[16];
  const float* biases = (const float*)d_in[17];
  const float* D1_W   = (const float*)d_in[18];
  const float* D1_b   = (const float*)d_in[19];
  const float* D23_W  = (const float*)d_in[20];
  const float* D23_b  = (const float*)d_in[21];
  const float* H1_W   = (const float*)d_in[22];
  const float* H1_b   = (const float*)d_in[23];
  const float* H2_W   = (const float*)d_in[24];
  const float* H2_b   = (const float*)d_in[25];
  const float* H3_W   = (const float*)d_in[26];
  const float* H3_b   = (const float*)d_in[27];

  // ---- workspace layout ----
  char* ws = (char*)d_ws;
  size_t o = 0;
  auto alloc = [&](size_t bytes)->char*{ char* p = ws + o; o = (o + bytes + 255) & ~(size_t)255; return p; };
  int*    deg     = (int*)   alloc(NNODES*4);
  int*    offs    = (int*)   alloc((NNODES+1)*4);
  int*    cur     = (int*)   alloc(NNODES*4);
  int*    part    = (int*)   alloc(NCHUNK*4);
  int*    csr_src = (int*)   alloc(NEDGES*4);
  float2* csr_ea  = (float2*)alloc(NEDGES*8);
  float*  xl      = (float*) alloc((size_t)NNODES*128*4);
  float*  xr      = (float*) alloc((size_t)NNODES*128*4);
  float*  bufA    = (float*) alloc((size_t)NNODES*128*4);
  float*  bufB    = (float*) alloc((size_t)NNODES*128*4);
  float*  pool    = (float*) alloc((NBATCH*128*2 + NBATCH)*4);
  float*  sums    = pool;
  float*  maxv    = pool + NBATCH*128;
  float*  cnt     = pool + NBATCH*256;
  (void)ws_size; (void)in_sizes; (void)n_in; (void)out_size;

  const int* src = eidx;
  const int* dst = eidx + NEDGES;

  // ---- CSR build ----
  hipMemsetAsync(deg, 0, NNODES*4, stream);
  hipMemsetAsync(pool, 0, (NBATCH*128*2 + NBATCH)*4, stream);
  hist_kernel<<<(NEDGES+255)/256, 256, 0, stream>>>(dst, deg);
  deg_partial<<<NCHUNK, SCAN_BLOCK, 0, stream>>>(deg, part);
  part_scan<<<1, 256, 0, stream>>>(part);
  scan_final<<<NCHUNK, SCAN_BLOCK, 0, stream>>>(deg, part, offs, cur);
  scatter_kernel<<<(NEDGES+255)/256, 256, 0, stream>>>(src, dst, eattr, cur, csr_src, csr_ea);

  // ---- conv0 ----
  gemm_k4_dual<<<(NNODES*128+255)/256, 256, 0, stream>>>(nodes, W0l, b0l, W0r, b0r, xl, xr);
  edge_kernel<<<(NNODES+3)/4, 256, 0, stream>>>(xl, xr, offs, csr_src, csr_ea,
                                                W0e, att0, bias0, nullptr, bufA);

  // ---- 4 skip blocks x 2 convs ----
  const int gemm_grid = (NNODES + 63) / 64;
  for(int blk=0; blk<4; blk++){
    int j = 2*blk;
    gemm_dual<<<gemm_grid, 256, 0, stream>>>(bufA, Wl + (size_t)j*16384, bl + j*128,
                                             Wr + (size_t)j*16384, br + j*128, xl, xr, NNODES);
    edge_kernel<<<(NNODES+3)/4, 256, 0, stream>>>(xl, xr, offs, csr_src, csr_ea,
                                                  We + j*256, atts + j*128, biases + j*128,
                                                  nullptr, bufB);
    j = 2*blk + 1;
    gemm_dual<<<gemm_grid, 256, 0, stream>>>(bufB, Wl + (size_t)j*16384, bl + j*128,
                                             Wr + (size_t)j*16384, br + j*128, xl, xr, NNODES);
    edge_kernel<<<(NNODES+3)/4, 256, 0, stream>>>(xl, xr, offs, csr_src, csr_ea,
                                                  We + j*256, atts + j*128, biases + j*128,
                                                  bufA /*residual*/, bufA);
  }

  // ---- pooling + fused dense trunk/heads ----
  pool_kernel<<<(NNODES + POOL_CHUNK - 1)/POOL_CHUNK, 128, 0, stream>>>(bufA, batch, sums, maxv, cnt);
  fused_dense<<<NBATCH, 128, 0, stream>>>(sums, maxv, cnt,
                                          D1_W, D1_b, D23_W, D23_b,
                                          H1_W, H1_b, H2_W, H2_b, H3_W, H3_b,
                                          (float*)d_out);
}

// Round 6
// 1482.775 us; speedup vs baseline: 1.7032x; 1.0516x over previous
//
#include <hip/hip_runtime.h>
#include <cmath>

#define NNODES 50000
#define NEDGES 600000
#define NBATCH 50
#define SCAN_BLOCK 256
#define NCHUNK ((NNODES + SCAN_BLOCK - 1) / SCAN_BLOCK)   // 196

// ============================ CSR build ============================
__global__ void hist_kernel(const int* __restrict__ dst, int* __restrict__ deg){
  int e = blockIdx.x*blockDim.x + threadIdx.x;
  if(e < NEDGES) atomicAdd(&deg[dst[e]], 1);
}

__global__ void deg_partial(const int* __restrict__ deg, int* __restrict__ part){
  __shared__ int red[SCAN_BLOCK];
  int t = threadIdx.x, id = blockIdx.x*SCAN_BLOCK + t;
  red[t] = (id < NNODES) ? deg[id] : 0;
  __syncthreads();
  for(int o = SCAN_BLOCK/2; o > 0; o >>= 1){
    if(t < o) red[t] += red[t+o];
    __syncthreads();
  }
  if(t == 0) part[blockIdx.x] = red[0];
}

__global__ void part_scan(int* __restrict__ part){
  __shared__ int ps[256];
  int t = threadIdx.x;
  int v = (t < NCHUNK) ? part[t] : 0;
  ps[t] = v; __syncthreads();
  for(int o=1;o<256;o<<=1){
    int u = (t>=o) ? ps[t-o] : 0;
    __syncthreads();
    ps[t] += u;
    __syncthreads();
  }
  if(t < NCHUNK) part[t] = ps[t] - v;   // exclusive
}

__global__ void scan_final(const int* __restrict__ deg, const int* __restrict__ part,
                           int* __restrict__ off, int* __restrict__ cur){
  __shared__ int ps[SCAN_BLOCK];
  int t = threadIdx.x, id = blockIdx.x*SCAN_BLOCK + t;
  int v = (id < NNODES) ? deg[id] : 0;
  ps[t] = v; __syncthreads();
  for(int o=1;o<SCAN_BLOCK;o<<=1){
    int u = (t>=o) ? ps[t-o] : 0;
    __syncthreads();
    ps[t] += u;
    __syncthreads();
  }
  int excl = ps[t] - v + part[blockIdx.x];
  if(id < NNODES){ off[id] = excl; cur[id] = excl; }
  if(id == 0) off[NNODES] = NEDGES;
}

__global__ void scatter_kernel(const int* __restrict__ src, const int* __restrict__ dst,
                               const float* __restrict__ ea, int* __restrict__ cur,
                               int* __restrict__ csr_src, float2* __restrict__ csr_ea){
  int e = blockIdx.x*blockDim.x + threadIdx.x;
  if(e >= NEDGES) return;
  int d = dst[e];
  int p = atomicAdd(&cur[d], 1);
  csr_src[p] = src[e];
  csr_ea[p] = make_float2(ea[2*e], ea[2*e+1]);
}

// ============================ conv0 linear (K=4), both outputs ============================
__global__ void gemm_k4_dual(const float* __restrict__ x,
                             const float* __restrict__ Wa, const float* __restrict__ ba,
                             const float* __restrict__ Wb, const float* __restrict__ bb,
                             float* __restrict__ outa, float* __restrict__ outb){
  int idx = blockIdx.x*blockDim.x + threadIdx.x;
  if(idx >= NNODES*128) return;
  int r = idx >> 7, c = idx & 127;
  float4 xv = *(const float4*)&x[r*4];
  float acca = ba[c] + xv.x*Wa[c] + xv.y*Wa[128+c] + xv.z*Wa[256+c] + xv.w*Wa[384+c];
  float accb = bb[c] + xv.x*Wb[c] + xv.y*Wb[128+c] + xv.z*Wb[256+c] + xv.w*Wb[384+c];
  outa[idx] = acca;
  outb[idx] = accb;
}

// ============================ dual GEMM: xl = x@Wa+ba, xr = x@Wb+bb ============================
// x-tile stored TRANSPOSED in LDS (xs[k][row], pad 65): stores are bank-(k+r)%32
// conflict-free; reads become 2x ds_read_b128 broadcast instead of 8x b32.
__launch_bounds__(256)
__global__ void gemm_dual(const float* __restrict__ x,
                          const float* __restrict__ Wa, const float* __restrict__ ba,
                          const float* __restrict__ Wb, const float* __restrict__ bb,
                          float* __restrict__ outa, float* __restrict__ outb, int M){
  __shared__ float xs[32][65];
  __shared__ float wsa[32][128];
  __shared__ float wsb[32][128];
  int tid = threadIdx.x;
  int tc = tid & 31, tr = tid >> 5;
  int row0 = blockIdx.x * 64;
  float acca[8][4], accb[8][4];
  #pragma unroll
  for(int i=0;i<8;i++){
    #pragma unroll
    for(int j=0;j<4;j++){ acca[i][j]=0.f; accb[i][j]=0.f; }
  }
  for(int kb=0;kb<128;kb+=32){
    #pragma unroll
    for(int i=0;i<8;i++){
      int l = tid + i*256;          // 0..2047
      int r = l >> 5, k = l & 31;
      int row = row0 + r;
      xs[k][r] = (row < M) ? x[row*128 + kb + k] : 0.f;
    }
    #pragma unroll
    for(int i=0;i<16;i++){
      int l = tid + i*256;          // 0..4095
      int k = l >> 7, c = l & 127;
      wsa[k][c] = Wa[(kb+k)*128 + c];
      wsb[k][c] = Wb[(kb+k)*128 + c];
    }
    __syncthreads();
    #pragma unroll 8
    for(int k=0;k<32;k++){
      float4 xv0 = *(float4*)&xs[k][tr*8];
      float4 xv1 = *(float4*)&xs[k][tr*8+4];
      float xv[8] = {xv0.x,xv0.y,xv0.z,xv0.w, xv1.x,xv1.y,xv1.z,xv1.w};
      float4 wa = *(float4*)&wsa[k][tc*4];
      float4 wb = *(float4*)&wsb[k][tc*4];
      #pragma unroll
      for(int i=0;i<8;i++){
        acca[i][0] += xv[i]*wa.x; acca[i][1] += xv[i]*wa.y;
        acca[i][2] += xv[i]*wa.z; acca[i][3] += xv[i]*wa.w;
        accb[i][0] += xv[i]*wb.x; accb[i][1] += xv[i]*wb.y;
        accb[i][2] += xv[i]*wb.z; accb[i][3] += xv[i]*wb.w;
      }
    }
    __syncthreads();
  }
  float4 bva = *(const float4*)&ba[tc*4];
  float4 bvb = *(const float4*)&bb[tc*4];
  #pragma unroll
  for(int i=0;i<8;i++){
    int row = row0 + tr*8 + i;
    if(row < M){
      float4 oa = make_float4(acca[i][0]+bva.x, acca[i][1]+bva.y, acca[i][2]+bva.z, acca[i][3]+bva.w);
      float4 ob = make_float4(accb[i][0]+bvb.x, accb[i][1]+bvb.y, accb[i][2]+bvb.z, accb[i][3]+bvb.w);
      *(float4*)&outa[row*128 + tc*4] = oa;
      *(float4*)&outb[row*128 + tc*4] = ob;
    }
  }
}

// ============================ fused GATv2 edge phase ============================
// One wave per destination node; lane l owns channels 2l,2l+1; 16-lane groups = heads.
// ILP=4 edges/iter (divides mean degree 12; ILP=8 regressed: VGPR 40, occ 53%).
__launch_bounds__(256)
__global__ void edge_kernel(const float* __restrict__ xl, const float* __restrict__ xr,
                            const int* __restrict__ off, const int* __restrict__ csr_src,
                            const float2* __restrict__ csr_ea,
                            const float* __restrict__ We, const float* __restrict__ att,
                            const float* __restrict__ bias, const float* __restrict__ res,
                            float* __restrict__ out){
  int wid  = (blockIdx.x*blockDim.x + threadIdx.x) >> 6;
  int lane = threadIdx.x & 63;
  if(wid >= NNODES) return;
  int node = wid;
  int c0 = lane*2;
  float2 xr2 = *(const float2*)&xr[node*128 + c0];
  float2 xls = *(const float2*)&xl[node*128 + c0];
  float2 av  = *(const float2*)&att[c0];
  float2 w0  = *(const float2*)&We[c0];
  float2 w1  = *(const float2*)&We[128 + c0];

  // self-loop (src=node, ea=0)
  float zx = xls.x + xr2.x; zx = zx > 0.f ? zx : 0.2f*zx;
  float zy = xls.y + xr2.y; zy = zy > 0.f ? zy : 0.2f*zy;
  float m = zx*av.x + zy*av.y;
  #pragma unroll
  for(int o=1;o<16;o<<=1) m += __shfl_xor(m, o, 64);
  float den = 1.f;
  float accx = xls.x, accy = xls.y;

  int e0 = off[node], e1 = off[node+1];
  for(int e=e0; e<e1; e+=4){
    int cnt = e1 - e;                       // wave-uniform
    int   s[4];
    float2 ea[4];
    #pragma unroll
    for(int j=0;j<4;j++){
      if(j < cnt){ s[j] = csr_src[e+j]; ea[j] = csr_ea[e+j]; }
      else       { s[j] = node;         ea[j] = make_float2(0.f,0.f); }
    }
    float2 xv[4];
    #pragma unroll
    for(int j=0;j<4;j++) xv[j] = *(const float2*)&xl[(size_t)s[j]*128 + c0];
    float p[4];
    #pragma unroll
    for(int j=0;j<4;j++){
      float z0 = xv[j].x + xr2.x + ea[j].x*w0.x + ea[j].y*w1.x; z0 = z0 > 0.f ? z0 : 0.2f*z0;
      float z1 = xv[j].y + xr2.y + ea[j].x*w0.y + ea[j].y*w1.y; z1 = z1 > 0.f ? z1 : 0.2f*z1;
      p[j] = z0*av.x + z1*av.y;
    }
    #pragma unroll
    for(int o=1;o<16;o<<=1){
      #pragma unroll
      for(int j=0;j<4;j++) p[j] += __shfl_xor(p[j], o, 64);
    }
    #pragma unroll
    for(int j=0;j<4;j++) if(j >= cnt) p[j] = -1e30f;
    float nm = m;
    #pragma unroll
    for(int j=0;j<4;j++) nm = fmaxf(nm, p[j]);
    float sc = __expf(m - nm);
    float pe[4];
    #pragma unroll
    for(int j=0;j<4;j++) pe[j] = __expf(p[j] - nm);
    den  = den*sc  + pe[0]+pe[1]+pe[2]+pe[3];
    accx = accx*sc + pe[0]*xv[0].x + pe[1]*xv[1].x + pe[2]*xv[2].x + pe[3]*xv[3].x;
    accy = accy*sc + pe[0]*xv[0].y + pe[1]*xv[1].y + pe[2]*xv[2].y + pe[3]*xv[3].y;
    m = nm;
  }
  float inv = 1.f/(den + 1e-16f);
  float ox = accx*inv + bias[c0];
  float oy = accy*inv + bias[c0+1];
  ox = ox > 0.f ? ox : 0.f;
  oy = oy > 0.f ? oy : 0.f;
  if(res){ ox += res[node*128 + c0]; oy += res[node*128 + c0 + 1]; }
  *(float2*)&out[node*128 + c0] = make_float2(ox, oy);
}

// ============================ pooling ============================
#define POOL_CHUNK 128
__launch_bounds__(128)
__global__ void pool_kernel(const float* __restrict__ x, const int* __restrict__ batch,
                            float* __restrict__ sums, float* __restrict__ maxv,
                            float* __restrict__ cnt){
  int c = threadIdx.x;
  int n0 = blockIdx.x * POOL_CHUNK;
  if(n0 >= NNODES) return;
  int n1 = n0 + POOL_CHUNK; if(n1 > NNODES) n1 = NNODES;
  int curb = batch[n0];
  float s = 0.f, mx = 0.f;
  float segc = 0.f;
  for(int nd = n0; nd < n1; nd++){
    int b = batch[nd];
    if(b != curb){
      atomicAdd(&sums[curb*128 + c], s);
      atomicMax((int*)&maxv[curb*128 + c], __float_as_int(mx));
      if(c == 0) atomicAdd(&cnt[curb], segc);
      curb = b; s = 0.f; mx = 0.f; segc = 0.f;
    }
    float v = x[nd*128 + c];
    s += v; mx = fmaxf(mx, v); segc += 1.f;
  }
  atomicAdd(&sums[curb*128 + c], s);
  atomicMax((int*)&maxv[curb*128 + c], __float_as_int(mx));
  if(c == 0) atomicAdd(&cnt[curb], segc);
}

// ============================ fused dense trunk + heads ============================
__launch_bounds__(128)
__global__ void fused_dense(const float* __restrict__ sums, const float* __restrict__ maxv,
                            const float* __restrict__ cnt,
                            const float* __restrict__ D1_W, const float* __restrict__ D1_b,
                            const float* __restrict__ D23_W, const float* __restrict__ D23_b,
                            const float* __restrict__ H1_W, const float* __restrict__ H1_b,
                            const float* __restrict__ H2_W, const float* __restrict__ H2_b,
                            const float* __restrict__ H3_W, const float* __restrict__ H3_b,
                            float* __restrict__ out){
  __shared__ float X[256];
  __shared__ float y[128];
  __shared__ float z[128];
  int b = blockIdx.x, t = threadIdx.x;
  float ct = cnt[b]; ct = ct > 1.f ? ct : 1.f;
  X[t]       = sums[b*128 + t] / ct;
  X[128 + t] = maxv[b*128 + t];
  __syncthreads();
  float acc = D1_b[t];
  #pragma unroll 16
  for(int k=0;k<256;k++) acc += X[k]*D1_W[k*128+t];
  y[t] = fmaxf(acc, 0.f);
  __syncthreads();
  acc = D23_b[t];
  #pragma unroll 16
  for(int k=0;k<128;k++) acc += y[k]*D23_W[k*128+t];
  z[t] = fmaxf(acc, 0.f);
  __syncthreads();
  acc = D23_b[128+t];
  #pragma unroll 16
  for(int k=0;k<128;k++) acc += z[k]*D23_W[16384 + k*128+t];
  y[t] = fmaxf(acc, 0.f);
  __syncthreads();
  for(int h=0;h<3;h++){
    acc = H1_b[h*128+t];
    #pragma unroll 16
    for(int k=0;k<128;k++) acc += y[k]*H1_W[h*16384 + k*128+t];
    z[t] = fmaxf(acc, 0.f);
    __syncthreads();
    float v = 0.f;
    if(t < 64){
      float a2 = H2_b[h*64+t];
      #pragma unroll 16
      for(int k=0;k<128;k++) a2 += z[k]*H2_W[h*8192 + k*64+t];
      a2 = fmaxf(a2, 0.f);
      v = a2 * H3_W[h*64 + t];
    }
    #pragma unroll
    for(int o=1;o<64;o<<=1) v += __shfl_xor(v, o, 64);
    if(t == 0){
      float r = v + H3_b[h];
      if(h == 0) r = tanhf(r);
      out[b*3 + h] = r;
    }
    __syncthreads();
  }
}

// ============================ launch ============================
extern "C" void kernel_launch(void* const* d_in, const int* in_sizes, int n_in,
                              void* d_out, int out_size, void* d_ws, size_t ws_size,
                              hipStream_t stream) {
  const float* nodes  = (const float*)d_in[0];
  const int*   eidx   = (const int*)  d_in[1];
  const float* eattr  = (const float*)d_in[2];
  const int*   batch  = (const int*)  d_in[3];
  const float* W0l    = (const float*)d_in[4];
  const float* b0l    = (const float*)d_in[5];
  const float* W0r    = (const float*)d_in[6];
  const float* b0r    = (const float*)d_in[7];
  const float* W0e    = (const float*)d_in[8];
  const float* att0   = (const float*)d_in[9];
  const float* bias0  = (const float*)d_in[10];
  const float* Wl     = (const float*)d_in[11];
  const float* bl     = (const float*)d_in[12];
  const float* Wr     = (const float*)d_in[13];
  const float* br     = (const float*)d_in[14];
  const float* We     = (const float*)d_in[15];
  const float* atts   = (const float*)d_in[16];
  const float* biases = (const float*)d_in[17];
  const float* D1_W   = (const float*)d_in[18];
  const float* D1_b   = (const float*)d_in[19];
  const float* D23_W  = (const float*)d_in[20];
  const float* D23_b  = (const float*)d_in[21];
  const float* H1_W   = (const float*)d_in[22];
  const float* H1_b   = (const float*)d_in[23];
  const float* H2_W   = (const float*)d_in[24];
  const float* H2_b   = (const float*)d_in[25];
  const float* H3_W   = (const float*)d_in[26];
  const float* H3_b   = (const float*)d_in[27];

  // ---- workspace layout ----
  char* ws = (char*)d_ws;
  size_t o = 0;
  auto alloc = [&](size_t bytes)->char*{ char* p = ws + o; o = (o + bytes + 255) & ~(size_t)255; return p; };
  int*    deg     = (int*)   alloc(NNODES*4);
  int*    offs    = (int*)   alloc((NNODES+1)*4);
  int*    cur     = (int*)   alloc(NNODES*4);
  int*    part    = (int*)   alloc(NCHUNK*4);
  int*    csr_src = (int*)   alloc(NEDGES*4);
  float2* csr_ea  = (float2*)alloc(NEDGES*8);
  float*  xl      = (float*) alloc((size_t)NNODES*128*4);
  float*  xr      = (float*) alloc((size_t)NNODES*128*4);
  float*  bufA    = (float*) alloc((size_t)NNODES*128*4);
  float*  bufB    = (float*) alloc((size_t)NNODES*128*4);
  float*  pool    = (float*) alloc((NBATCH*128*2 + NBATCH)*4);
  float*  sums    = pool;
  float*  maxv    = pool + NBATCH*128;
  float*  cnt     = pool + NBATCH*256;
  (void)ws_size; (void)in_sizes; (void)n_in; (void)out_size;

  const int* src = eidx;
  const int* dst = eidx + NEDGES;

  // ---- CSR build ----
  hipMemsetAsync(deg, 0, NNODES*4, stream);
  hipMemsetAsync(pool, 0, (NBATCH*128*2 + NBATCH)*4, stream);
  hist_kernel<<<(NEDGES+255)/256, 256, 0, stream>>>(dst, deg);
  deg_partial<<<NCHUNK, SCAN_BLOCK, 0, stream>>>(deg, part);
  part_scan<<<1, 256, 0, stream>>>(part);
  scan_final<<<NCHUNK, SCAN_BLOCK, 0, stream>>>(deg, part, offs, cur);
  scatter_kernel<<<(NEDGES+255)/256, 256, 0, stream>>>(src, dst, eattr, cur, csr_src, csr_ea);

  // ---- conv0 ----
  gemm_k4_dual<<<(NNODES*128+255)/256, 256, 0, stream>>>(nodes, W0l, b0l, W0r, b0r, xl, xr);
  edge_kernel<<<(NNODES+3)/4, 256, 0, stream>>>(xl, xr, offs, csr_src, csr_ea,
                                                W0e, att0, bias0, nullptr, bufA);

  // ---- 4 skip blocks x 2 convs ----
  const int gemm_grid = (NNODES + 63) / 64;
  for(int blk=0; blk<4; blk++){
    int j = 2*blk;
    gemm_dual<<<gemm_grid, 256, 0, stream>>>(bufA, Wl + (size_t)j*16384, bl + j*128,
                                             Wr + (size_t)j*16384, br + j*128, xl, xr, NNODES);
    edge_kernel<<<(NNODES+3)/4, 256, 0, stream>>>(xl, xr, offs, csr_src, csr_ea,
                                                  We + j*256, atts + j*128, biases + j*128,
                                                  nullptr, bufB);
    j = 2*blk + 1;
    gemm_dual<<<gemm_grid, 256, 0, stream>>>(bufB, Wl + (size_t)j*16384, bl + j*128,
                                             Wr + (size_t)j*16384, br + j*128, xl, xr, NNODES);
    edge_kernel<<<(NNODES+3)/4, 256, 0, stream>>>(xl, xr, offs, csr_src, csr_ea,
                                                  We + j*256, atts + j*128, biases + j*128,
                                                  bufA /*residual*/, bufA);
  }

  // ---- pooling + fused dense trunk/heads ----
  pool_kernel<<<(NNODES + POOL_CHUNK - 1)/POOL_CHUNK, 128, 0, stream>>>(bufA, batch, sums, maxv, cnt);
  fused_dense<<<NBATCH, 128, 0, stream>>>(sums, maxv, cnt,
                                          D1_W, D1_b, D23_W, D23_b,
                                          H1_W, H1_b, H2_W, H2_b, H3_W, H3_b,
                                          (float*)d_out);
}

// Round 7
// 1330.077 us; speedup vs baseline: 1.8987x; 1.1148x over previous
//
#include <hip/hip_runtime.h>
#include <cmath>

#define NNODES 50000
#define NEDGES 600000
#define NBATCH 50
#define SCAN_BLOCK 256
#define NCHUNK ((NNODES + SCAN_BLOCK - 1) / SCAN_BLOCK)   // 196

// ============================ CSR build ============================
__global__ void hist_kernel(const int* __restrict__ dst, int* __restrict__ deg){
  int e = blockIdx.x*blockDim.x + threadIdx.x;
  if(e < NEDGES) atomicAdd(&deg[dst[e]], 1);
}

__global__ void deg_partial(const int* __restrict__ deg, int* __restrict__ part){
  __shared__ int red[SCAN_BLOCK];
  int t = threadIdx.x, id = blockIdx.x*SCAN_BLOCK + t;
  red[t] = (id < NNODES) ? deg[id] : 0;
  __syncthreads();
  for(int o = SCAN_BLOCK/2; o > 0; o >>= 1){
    if(t < o) red[t] += red[t+o];
    __syncthreads();
  }
  if(t == 0) part[blockIdx.x] = red[0];
}

__global__ void part_scan(int* __restrict__ part){
  __shared__ int ps[256];
  int t = threadIdx.x;
  int v = (t < NCHUNK) ? part[t] : 0;
  ps[t] = v; __syncthreads();
  for(int o=1;o<256;o<<=1){
    int u = (t>=o) ? ps[t-o] : 0;
    __syncthreads();
    ps[t] += u;
    __syncthreads();
  }
  if(t < NCHUNK) part[t] = ps[t] - v;   // exclusive
}

__global__ void scan_final(const int* __restrict__ deg, const int* __restrict__ part,
                           int* __restrict__ off, int* __restrict__ cur){
  __shared__ int ps[SCAN_BLOCK];
  int t = threadIdx.x, id = blockIdx.x*SCAN_BLOCK + t;
  int v = (id < NNODES) ? deg[id] : 0;
  ps[t] = v; __syncthreads();
  for(int o=1;o<SCAN_BLOCK;o<<=1){
    int u = (t>=o) ? ps[t-o] : 0;
    __syncthreads();
    ps[t] += u;
    __syncthreads();
  }
  int excl = ps[t] - v + part[blockIdx.x];
  if(id < NNODES){ off[id] = excl; cur[id] = excl; }
  if(id == 0) off[NNODES] = NEDGES;
}

__global__ void scatter_kernel(const int* __restrict__ src, const int* __restrict__ dst,
                               const float* __restrict__ ea, int* __restrict__ cur,
                               int* __restrict__ csr_src, float2* __restrict__ csr_ea){
  int e = blockIdx.x*blockDim.x + threadIdx.x;
  if(e >= NEDGES) return;
  int d = dst[e];
  int p = atomicAdd(&cur[d], 1);
  csr_src[p] = src[e];
  csr_ea[p] = make_float2(ea[2*e], ea[2*e+1]);
}

// ============================ conv0 linear (K=4), both outputs ============================
__global__ void gemm_k4_dual(const float* __restrict__ x,
                             const float* __restrict__ Wa, const float* __restrict__ ba,
                             const float* __restrict__ Wb, const float* __restrict__ bb,
                             float* __restrict__ outa, float* __restrict__ outb){
  int idx = blockIdx.x*blockDim.x + threadIdx.x;
  if(idx >= NNODES*128) return;
  int r = idx >> 7, c = idx & 127;
  float4 xv = *(const float4*)&x[r*4];
  float acca = ba[c] + xv.x*Wa[c] + xv.y*Wa[128+c] + xv.z*Wa[256+c] + xv.w*Wa[384+c];
  float accb = bb[c] + xv.x*Wb[c] + xv.y*Wb[128+c] + xv.z*Wb[256+c] + xv.w*Wb[384+c];
  outa[idx] = acca;
  outb[idx] = accb;
}

// ============================ dual GEMM: xl = x@Wa+ba, xr = x@Wb+bb ============================
__launch_bounds__(256)
__global__ void gemm_dual(const float* __restrict__ x,
                          const float* __restrict__ Wa, const float* __restrict__ ba,
                          const float* __restrict__ Wb, const float* __restrict__ bb,
                          float* __restrict__ outa, float* __restrict__ outb, int M){
  __shared__ float xs[32][65];
  __shared__ float wsa[32][128];
  __shared__ float wsb[32][128];
  int tid = threadIdx.x;
  int tc = tid & 31, tr = tid >> 5;
  int row0 = blockIdx.x * 64;
  float acca[8][4], accb[8][4];
  #pragma unroll
  for(int i=0;i<8;i++){
    #pragma unroll
    for(int j=0;j<4;j++){ acca[i][j]=0.f; accb[i][j]=0.f; }
  }
  for(int kb=0;kb<128;kb+=32){
    #pragma unroll
    for(int i=0;i<8;i++){
      int l = tid + i*256;
      int r = l >> 5, k = l & 31;
      int row = row0 + r;
      xs[k][r] = (row < M) ? x[row*128 + kb + k] : 0.f;
    }
    #pragma unroll
    for(int i=0;i<16;i++){
      int l = tid + i*256;
      int k = l >> 7, c = l & 127;
      wsa[k][c] = Wa[(kb+k)*128 + c];
      wsb[k][c] = Wb[(kb+k)*128 + c];
    }
    __syncthreads();
    #pragma unroll 8
    for(int k=0;k<32;k++){
      float4 xv0 = *(float4*)&xs[k][tr*8];
      float4 xv1 = *(float4*)&xs[k][tr*8+4];
      float xv[8] = {xv0.x,xv0.y,xv0.z,xv0.w, xv1.x,xv1.y,xv1.z,xv1.w};
      float4 wa = *(float4*)&wsa[k][tc*4];
      float4 wb = *(float4*)&wsb[k][tc*4];
      #pragma unroll
      for(int i=0;i<8;i++){
        acca[i][0] += xv[i]*wa.x; acca[i][1] += xv[i]*wa.y;
        acca[i][2] += xv[i]*wa.z; acca[i][3] += xv[i]*wa.w;
        accb[i][0] += xv[i]*wb.x; accb[i][1] += xv[i]*wb.y;
        accb[i][2] += xv[i]*wb.z; accb[i][3] += xv[i]*wb.w;
      }
    }
    __syncthreads();
  }
  float4 bva = *(const float4*)&ba[tc*4];
  float4 bvb = *(const float4*)&bb[tc*4];
  #pragma unroll
  for(int i=0;i<8;i++){
    int row = row0 + tr*8 + i;
    if(row < M){
      float4 oa = make_float4(acca[i][0]+bva.x, acca[i][1]+bva.y, acca[i][2]+bva.z, acca[i][3]+bva.w);
      float4 ob = make_float4(accb[i][0]+bvb.x, accb[i][1]+bvb.y, accb[i][2]+bvb.z, accb[i][3]+bvb.w);
      *(float4*)&outa[row*128 + tc*4] = oa;
      *(float4*)&outb[row*128 + tc*4] = ob;
    }
  }
}

// ============================ fused GATv2 edge phase ============================
// One wave per destination node; lane l owns channels 2l,2l+1; 16-lane groups = heads.
// ILP=4 edges/iter. node forced into SGPR via readfirstlane so off/csr_src/csr_ea
// become scalar loads and tail checks become scalar branches (compiler can't
// prove tid>>6 wave-uniform on its own).
__launch_bounds__(256)
__global__ void edge_kernel(const float* __restrict__ xl, const float* __restrict__ xr,
                            const int* __restrict__ off, const int* __restrict__ csr_src,
                            const float2* __restrict__ csr_ea,
                            const float* __restrict__ We, const float* __restrict__ att,
                            const float* __restrict__ bias, const float* __restrict__ res,
                            float* __restrict__ out){
  int wid  = (blockIdx.x*blockDim.x + threadIdx.x) >> 6;
  int lane = threadIdx.x & 63;
  if(wid >= NNODES) return;
  int node = __builtin_amdgcn_readfirstlane(wid);   // provably wave-uniform
  int c0 = lane*2;
  float2 xr2 = *(const float2*)&xr[node*128 + c0];
  float2 xls = *(const float2*)&xl[node*128 + c0];
  float2 av  = *(const float2*)&att[c0];
  float2 w0  = *(const float2*)&We[c0];
  float2 w1  = *(const float2*)&We[128 + c0];

  // self-loop (src=node, ea=0)
  float zx = xls.x + xr2.x; zx = zx > 0.f ? zx : 0.2f*zx;
  float zy = xls.y + xr2.y; zy = zy > 0.f ? zy : 0.2f*zy;
  float m = zx*av.x + zy*av.y;
  #pragma unroll
  for(int o=1;o<16;o<<=1) m += __shfl_xor(m, o, 64);
  float den = 1.f;
  float accx = xls.x, accy = xls.y;

  int e0 = off[node], e1 = off[node+1];
  for(int e=e0; e<e1; e+=4){
    int cnt = e1 - e;                       // scalar
    int   s[4];
    float2 ea[4];
    #pragma unroll
    for(int j=0;j<4;j++){
      if(j < cnt){
        s[j]  = __builtin_amdgcn_readfirstlane(csr_src[e+j]);
        ea[j] = csr_ea[e+j];
      } else {
        s[j] = node; ea[j] = make_float2(0.f,0.f);
      }
    }
    float2 xv[4];
    #pragma unroll
    for(int j=0;j<4;j++) xv[j] = *(const float2*)&xl[(size_t)s[j]*128 + c0];
    float p[4];
    #pragma unroll
    for(int j=0;j<4;j++){
      float z0 = xv[j].x + xr2.x + ea[j].x*w0.x + ea[j].y*w1.x; z0 = z0 > 0.f ? z0 : 0.2f*z0;
      float z1 = xv[j].y + xr2.y + ea[j].x*w0.y + ea[j].y*w1.y; z1 = z1 > 0.f ? z1 : 0.2f*z1;
      p[j] = z0*av.x + z1*av.y;
    }
    #pragma unroll
    for(int o=1;o<16;o<<=1){
      #pragma unroll
      for(int j=0;j<4;j++) p[j] += __shfl_xor(p[j], o, 64);
    }
    #pragma unroll
    for(int j=0;j<4;j++) if(j >= cnt) p[j] = -1e30f;
    float nm = m;
    #pragma unroll
    for(int j=0;j<4;j++) nm = fmaxf(nm, p[j]);
    float sc = __expf(m - nm);
    float pe[4];
    #pragma unroll
    for(int j=0;j<4;j++) pe[j] = __expf(p[j] - nm);
    den  = den*sc  + pe[0]+pe[1]+pe[2]+pe[3];
    accx = accx*sc + pe[0]*xv[0].x + pe[1]*xv[1].x + pe[2]*xv[2].x + pe[3]*xv[3].x;
    accy = accy*sc + pe[0]*xv[0].y + pe[1]*xv[1].y + pe[2]*xv[2].y + pe[3]*xv[3].y;
    m = nm;
  }
  float inv = 1.f/(den + 1e-16f);
  float ox = accx*inv + bias[c0];
  float oy = accy*inv + bias[c0+1];
  ox = ox > 0.f ? ox : 0.f;
  oy = oy > 0.f ? oy : 0.f;
  if(res){ ox += res[node*128 + c0]; oy += res[node*128 + c0 + 1]; }
  *(float2*)&out[node*128 + c0] = make_float2(ox, oy);
}

// ============================ pooling ============================
#define POOL_CHUNK 128
__launch_bounds__(128)
__global__ void pool_kernel(const float* __restrict__ x, const int* __restrict__ batch,
                            float* __restrict__ sums, float* __restrict__ maxv,
                            float* __restrict__ cnt){
  int c = threadIdx.x;
  int n0 = blockIdx.x * POOL_CHUNK;
  if(n0 >= NNODES) return;
  int n1 = n0 + POOL_CHUNK; if(n1 > NNODES) n1 = NNODES;
  int curb = batch[n0];
  float s = 0.f, mx = 0.f;
  float segc = 0.f;
  for(int nd = n0; nd < n1; nd++){
    int b = batch[nd];
    if(b != curb){
      atomicAdd(&sums[curb*128 + c], s);
      atomicMax((int*)&maxv[curb*128 + c], __float_as_int(mx));
      if(c == 0) atomicAdd(&cnt[curb], segc);
      curb = b; s = 0.f; mx = 0.f; segc = 0.f;
    }
    float v = x[nd*128 + c];
    s += v; mx = fmaxf(mx, v); segc += 1.f;
  }
  atomicAdd(&sums[curb*128 + c], s);
  atomicMax((int*)&maxv[curb*128 + c], __float_as_int(mx));
  if(c == 0) atomicAdd(&cnt[curb], segc);
}

// ============================ fused dense trunk + heads ============================
__launch_bounds__(128)
__global__ void fused_dense(const float* __restrict__ sums, const float* __restrict__ maxv,
                            const float* __restrict__ cnt,
                            const float* __restrict__ D1_W, const float* __restrict__ D1_b,
                            const float* __restrict__ D23_W, const float* __restrict__ D23_b,
                            const float* __restrict__ H1_W, const float* __restrict__ H1_b,
                            const float* __restrict__ H2_W, const float* __restrict__ H2_b,
                            const float* __restrict__ H3_W, const float* __restrict__ H3_b,
                            float* __restrict__ out){
  __shared__ float X[256];
  __shared__ float y[128];
  __shared__ float z[128];
  int b = blockIdx.x, t = threadIdx.x;
  float ct = cnt[b]; ct = ct > 1.f ? ct : 1.f;
  X[t]       = sums[b*128 + t] / ct;
  X[128 + t] = maxv[b*128 + t];
  __syncthreads();
  float acc = D1_b[t];
  #pragma unroll 16
  for(int k=0;k<256;k++) acc += X[k]*D1_W[k*128+t];
  y[t] = fmaxf(acc, 0.f);
  __syncthreads();
  acc = D23_b[t];
  #pragma unroll 16
  for(int k=0;k<128;k++) acc += y[k]*D23_W[k*128+t];
  z[t] = fmaxf(acc, 0.f);
  __syncthreads();
  acc = D23_b[128+t];
  #pragma unroll 16
  for(int k=0;k<128;k++) acc += z[k]*D23_W[16384 + k*128+t];
  y[t] = fmaxf(acc, 0.f);
  __syncthreads();
  for(int h=0;h<3;h++){
    acc = H1_b[h*128+t];
    #pragma unroll 16
    for(int k=0;k<128;k++) acc += y[k]*H1_W[h*16384 + k*128+t];
    z[t] = fmaxf(acc, 0.f);
    __syncthreads();
    float v = 0.f;
    if(t < 64){
      float a2 = H2_b[h*64+t];
      #pragma unroll 16
      for(int k=0;k<128;k++) a2 += z[k]*H2_W[h*8192 + k*64+t];
      a2 = fmaxf(a2, 0.f);
      v = a2 * H3_W[h*64 + t];
    }
    #pragma unroll
    for(int o=1;o<64;o<<=1) v += __shfl_xor(v, o, 64);
    if(t == 0){
      float r = v + H3_b[h];
      if(h == 0) r = tanhf(r);
      out[b*3 + h] = r;
    }
    __syncthreads();
  }
}

// ============================ launch ============================
extern "C" void kernel_launch(void* const* d_in, const int* in_sizes, int n_in,
                              void* d_out, int out_size, void* d_ws, size_t ws_size,
                              hipStream_t stream) {
  const float* nodes  = (const float*)d_in[0];
  const int*   eidx   = (const int*)  d_in[1];
  const float* eattr  = (const float*)d_in[2];
  const int*   batch  = (const int*)  d_in[3];
  const float* W0l    = (const float*)d_in[4];
  const float* b0l    = (const float*)d_in[5];
  const float* W0r    = (const float*)d_in[6];
  const float* b0r    = (const float*)d_in[7];
  const float* W0e    = (const float*)d_in[8];
  const float* att0   = (const float*)d_in[9];
  const float* bias0  = (const float*)d_in[10];
  const float* Wl     = (const float*)d_in[11];
  const float* bl     = (const float*)d_in[12];
  const float* Wr     = (const float*)d_in[13];
  const float* br     = (const float*)d_in[14];
  const float* We     = (const float*)d_in[15];
  const float* atts   = (const float*)d_in[16];
  const float* biases = (const float*)d_in[17];
  const float* D1_W   = (const float*)d_in[18];
  const float* D1_b   = (const float*)d_in[19];
  const float* D23_W  = (const float*)d_in[20];
  const float* D23_b  = (const float*)d_in[21];
  const float* H1_W   = (const float*)d_in[22];
  const float* H1_b   = (const float*)d_in[23];
  const float* H2_W   = (const float*)d_in[24];
  const float* H2_b   = (const float*)d_in[25];
  const float* H3_W   = (const float*)d_in[26];
  const float* H3_b   = (const float*)d_in[27];

  // ---- workspace layout ----
  char* ws = (char*)d_ws;
  size_t o = 0;
  auto alloc = [&](size_t bytes)->char*{ char* p = ws + o; o = (o + bytes + 255) & ~(size_t)255; return p; };
  int*    deg     = (int*)   alloc(NNODES*4);
  int*    offs    = (int*)   alloc((NNODES+1)*4);
  int*    cur     = (int*)   alloc(NNODES*4);
  int*    part    = (int*)   alloc(NCHUNK*4);
  int*    csr_src = (int*)   alloc(NEDGES*4);
  float2* csr_ea  = (float2*)alloc(NEDGES*8);
  float*  xl      = (float*) alloc((size_t)NNODES*128*4);
  float*  xr      = (float*) alloc((size_t)NNODES*128*4);
  float*  bufA    = (float*) alloc((size_t)NNODES*128*4);
  float*  bufB    = (float*) alloc((size_t)NNODES*128*4);
  float*  pool    = (float*) alloc((NBATCH*128*2 + NBATCH)*4);
  float*  sums    = pool;
  float*  maxv    = pool + NBATCH*128;
  float*  cnt     = pool + NBATCH*256;
  (void)ws_size; (void)in_sizes; (void)n_in; (void)out_size;

  const int* src = eidx;
  const int* dst = eidx + NEDGES;

  // ---- CSR build ----
  hipMemsetAsync(deg, 0, NNODES*4, stream);
  hipMemsetAsync(pool, 0, (NBATCH*128*2 + NBATCH)*4, stream);
  hist_kernel<<<(NEDGES+255)/256, 256, 0, stream>>>(dst, deg);
  deg_partial<<<NCHUNK, SCAN_BLOCK, 0, stream>>>(deg, part);
  part_scan<<<1, 256, 0, stream>>>(part);
  scan_final<<<NCHUNK, SCAN_BLOCK, 0, stream>>>(deg, part, offs, cur);
  scatter_kernel<<<(NEDGES+255)/256, 256, 0, stream>>>(src, dst, eattr, cur, csr_src, csr_ea);

  // ---- conv0 ----
  gemm_k4_dual<<<(NNODES*128+255)/256, 256, 0, stream>>>(nodes, W0l, b0l, W0r, b0r, xl, xr);
  edge_kernel<<<(NNODES+3)/4, 256, 0, stream>>>(xl, xr, offs, csr_src, csr_ea,
                                                W0e, att0, bias0, nullptr, bufA);

  // ---- 4 skip blocks x 2 convs ----
  const int gemm_grid = (NNODES + 63) / 64;
  for(int blk=0; blk<4; blk++){
    int j = 2*blk;
    gemm_dual<<<gemm_grid, 256, 0, stream>>>(bufA, Wl + (size_t)j*16384, bl + j*128,
                                             Wr + (size_t)j*16384, br + j*128, xl, xr, NNODES);
    edge_kernel<<<(NNODES+3)/4, 256, 0, stream>>>(xl, xr, offs, csr_src, csr_ea,
                                                  We + j*256, atts + j*128, biases + j*128,
                                                  nullptr, bufB);
    j = 2*blk + 1;
    gemm_dual<<<gemm_grid, 256, 0, stream>>>(bufB, Wl + (size_t)j*16384, bl + j*128,
                                             Wr + (size_t)j*16384, br + j*128, xl, xr, NNODES);
    edge_kernel<<<(NNODES+3)/4, 256, 0, stream>>>(xl, xr, offs, csr_src, csr_ea,
                                                  We + j*256, atts + j*128, biases + j*128,
                                                  bufA /*residual*/, bufA);
  }

  // ---- pooling + fused dense trunk/heads ----
  pool_kernel<<<(NNODES + POOL_CHUNK - 1)/POOL_CHUNK, 128, 0, stream>>>(bufA, batch, sums, maxv, cnt);
  fused_dense<<<NBATCH, 128, 0, stream>>>(sums, maxv, cnt,
                                          D1_W, D1_b, D23_W, D23_b,
                                          H1_W, H1_b, H2_W, H2_b, H3_W, H3_b,
                                          (float*)d_out);
}